// Round 15
// baseline (374.832 us; speedup 1.0000x reference)
//
#include <hip/hip_runtime.h>
#include <hip/hip_bf16.h>
#include <math.h>

typedef unsigned int uint;
typedef unsigned short ushort_t;
typedef __bf16 bf16_t;
typedef bf16_t bf16x8 __attribute__((ext_vector_type(8)));
typedef float f32x4 __attribute__((ext_vector_type(4)));
typedef float f32x2 __attribute__((ext_vector_type(2)));

__device__ inline float2 bf2_unpack(uint u) {
    union { uint i; float f; } a, b;
    a.i = u << 16;
    b.i = u & 0xffff0000u;
    return make_float2(a.f, b.f);   // (lo, hi)
}

__device__ inline uint bf2_pack(float lo, float hi) {
    __hip_bfloat162 h;
    h.x = __float2bfloat16(lo);
    h.y = __float2bfloat16(hi);
    return *(uint*)&h;              // hi<<16 | lo
}

// fp8 e4m3 (OCP) pack/unpack via HW converts (word selector must be compile-time const)
template<bool WORD>
__device__ __forceinline__ float2 fp8x2_unpack(uint u) {
    f32x2 r = __builtin_amdgcn_cvt_pk_f32_fp8((int)u, WORD);
    return make_float2(r[0], r[1]);
}
__device__ __forceinline__ int fp8x2_pack(float a, float b) {
    return __builtin_amdgcn_cvt_pk_fp8_f32(a, b, 0, false);  // bytes [a,b] in low 16
}

__device__ inline void store_out(float* p, float v) { *p = v; }
__device__ inline void store_out(__hip_bfloat16* p, float v) { *p = __float2bfloat16(v); }

#define RFL(x) __builtin_amdgcn_readfirstlane(x)

#define SCL_XW 32.f
#define SCL_KV 16.f
#define BK_SH 5               // 32 dst nodes per bucket
#define CHUNK 16384           // edges per binning block

// ---------------- bucketed CSR build: LDS-histogram binning (low-contention) ----------------
__global__ __launch_bounds__(1024) void k_bcount(const int* __restrict__ ei, int* __restrict__ bcnt,
                                                 int E, int nbk) {
    __shared__ int hist[2048];
    int t = threadIdx.x;
    for (int i = t; i < nbk; i += 1024) hist[i] = 0;
    __syncthreads();
    int e0 = blockIdx.x * CHUNK;
    int e1 = e0 + CHUNK; if (e1 > E) e1 = E;
    for (int e = e0 + t; e < e1; e += 1024)
        atomicAdd(&hist[(uint)ei[E + e] >> BK_SH], 1);
    __syncthreads();
    for (int i = t; i < nbk; i += 1024) {
        int c = hist[i];
        if (c) atomicAdd(&bcnt[i], c);
    }
}

// single-block chunked exclusive scan over nbk buckets; boff[nbk] = E
__global__ __launch_bounds__(1024) void k_bscan(const int* __restrict__ bcnt, int* __restrict__ boff, int nbk) {
    __shared__ int tmp[1024];
    int t = threadIdx.x;
    int per = (nbk + 1023) >> 10;
    int s0 = t * per, s1 = s0 + per; if (s1 > nbk) s1 = nbk;
    int sum = 0;
    for (int i = s0; i < s1; ++i) sum += bcnt[i];
    tmp[t] = sum;
    __syncthreads();
    for (int d = 1; d < 1024; d <<= 1) {
        int a = (t >= d) ? tmp[t - d] : 0;
        __syncthreads();
        tmp[t] += a;
        __syncthreads();
    }
    int carry = tmp[t] - sum;
    for (int i = s0; i < s1; ++i) { boff[i] = carry; carry += bcnt[i]; }
    if (t == 1023) boff[nbk] = tmp[1023];
}

// binned scatter: per-block LDS histogram -> one reservation atomic per (block,bucket) -> run writes
__global__ __launch_bounds__(1024) void k_bfill(const int* __restrict__ ei, const int* __restrict__ boff,
                                                int* __restrict__ bcur, uint2* __restrict__ pairs,
                                                int E, int nbk) {
    __shared__ int hist[2048];
    __shared__ int basep[2048];
    int t = threadIdx.x;
    for (int i = t; i < nbk; i += 1024) hist[i] = 0;
    __syncthreads();
    int e0 = blockIdx.x * CHUNK;
    int e1 = e0 + CHUNK; if (e1 > E) e1 = E;
    for (int e = e0 + t; e < e1; e += 1024)
        atomicAdd(&hist[(uint)ei[E + e] >> BK_SH], 1);
    __syncthreads();
    for (int i = t; i < nbk; i += 1024) {
        int c = hist[i];
        basep[i] = c ? atomicAdd(&bcur[i], c) : 0;
        hist[i] = 0;                                   // reuse as local cursor
    }
    __syncthreads();
    for (int e = e0 + t; e < e1; e += 1024) {
        int d = ei[E + e];
        int s = ei[e];
        int b = (uint)d >> BK_SH;
        int p = atomicAdd(&hist[b], 1);                // LDS cursor
        pairs[boff[b] + basep[b] + p] = make_uint2((uint)d, (uint)s);
    }
}

// one block per bucket: LDS per-dst count + scan -> off/dinv; then local scatter of col
__global__ __launch_bounds__(256) void k_bucket(const uint2* __restrict__ pairs, const int* __restrict__ boff,
                                                int* __restrict__ off, float* __restrict__ dinv,
                                                int* __restrict__ col, int N, int nbk, int E) {
    int b = blockIdx.x, t = threadIdx.x;
    __shared__ int cnt[32], excl[32], cur[32];
    int base = boff[b], end = boff[b + 1];
    if (t < 32) cnt[t] = 0;
    __syncthreads();
    for (int i = base + t; i < end; i += 256) {
        uint2 p = pairs[i];
        atomicAdd(&cnt[p.x & 31], 1);
    }
    __syncthreads();
    if (t == 0) {
        int run = base;
        #pragma unroll
        for (int j = 0; j < 32; ++j) { excl[j] = run; cur[j] = run; run += cnt[j]; }
    }
    __syncthreads();
    if (t < 32) {
        int node = (b << BK_SH) + t;
        if (node < N) {
            off[node] = excl[t];
            dinv[node] = rsqrtf((float)(cnt[t] + 1));   // self-loop adds 1
        }
    }
    if (b == nbk - 1 && t == 0) off[N] = E;
    for (int i = base + t; i < end; i += 256) {
        uint2 p = pairs[i];
        int pos = atomicAdd(&cur[p.x & 31], 1);
        col[pos] = (int)p.y;
    }
}

// ---------------- fp32 -> bf16 weight conversion (6 x 128x128 mats) ----------------
__global__ __launch_bounds__(256) void k_cvt6(const float* __restrict__ s0, const float* __restrict__ s1,
                                              const float* __restrict__ s2, const float* __restrict__ s3,
                                              const float* __restrict__ s4, const float* __restrict__ s5,
                                              __hip_bfloat16* __restrict__ dst) {
    int i = blockIdx.x * 256 + threadIdx.x;
    if (i >= 6 * 16384) return;
    int m = i >> 14;
    const float* s = (m == 0) ? s0 : (m == 1) ? s1 : (m == 2) ? s2 : (m == 3) ? s3 : (m == 4) ? s4 : s5;
    dst[i] = __float2bfloat16(s[i & 16383]);
}

// ---------------- scalar linear for FI=32 (embed), bf16 out ----------------
template<int FI, bool BIAS, bool RELU, typename OUT>
__global__ __launch_bounds__(256) void k_linear(const float* __restrict__ x, const float* __restrict__ W,
                                                const float* __restrict__ b, OUT* __restrict__ y, int n) {
    __shared__ float4 Wt4[(FI / 4) * 128];
    __shared__ float4 xl[2][FI / 4];
    int t = threadIdx.x & 127;
    int h = threadIdx.x >> 7;
    {
        const float4* Wrow = (const float4*)(W + (size_t)t * FI);
        #pragma unroll
        for (int k4 = h * (FI / 8); k4 < (h + 1) * (FI / 8); ++k4) Wt4[k4 * 128 + t] = Wrow[k4];
    }
    float bias = 0.f;
    if (BIAS) bias = b[t];
    __syncthreads();
    for (int n0 = blockIdx.x * 2; n0 < n; n0 += gridDim.x * 2) {
        int nn = n0 + h;
        if (nn < n && t < FI / 4) xl[h][t] = ((const float4*)(x + (size_t)nn * FI))[t];
        __syncthreads();
        if (nn < n) {
            float acc = bias;
            #pragma unroll
            for (int k4 = 0; k4 < FI / 4; ++k4) {
                float4 xv = xl[h][k4];
                float4 wv = Wt4[k4 * 128 + t];
                acc += xv.x * wv.x + xv.y * wv.y + xv.z * wv.z + xv.w * wv.w;
            }
            if (RELU) acc = fmaxf(acc, 0.f);
            store_out(&y[(size_t)nn * 128 + t], acc);
        }
        __syncthreads();
    }
}

// ---------------- MFMA linear with per-row dinv prescale, fp8 x SCL_XW output ----------------
__global__ __launch_bounds__(256) void k_lin_mfma_scale(const __hip_bfloat16* __restrict__ X,
                                                        const __hip_bfloat16* __restrict__ W,
                                                        const float* __restrict__ dinv,
                                                        ushort_t* __restrict__ XW8, int n) {
    int wave = threadIdx.x >> 6, lane = threadIdx.x & 63;
    int r0 = blockIdx.x * 64 + wave * 16;
    if (r0 >= n) return;
    int mrow = r0 + (lane & 15);
    if (mrow >= n) mrow = n - 1;
    int kk4 = lane >> 4;
    const bf16x8* xr = (const bf16x8*)((const bf16_t*)X + (size_t)mrow * 128);
    bf16x8 a0 = xr[0 * 4 + kk4];
    bf16x8 a1 = xr[1 * 4 + kk4];
    bf16x8 a2 = xr[2 * 4 + kk4];
    bf16x8 a3 = xr[3 * 4 + kk4];
    int orow = (lane >> 4) * 4;
    int ocol = lane & 15;
    float dv[4];
    #pragma unroll
    for (int j = 0; j < 4; ++j) {
        int row = r0 + orow + j;
        dv[j] = ((row < n) ? dinv[row] : 0.f) * SCL_XW;
    }
    #pragma unroll
    for (int c = 0; c < 8; ++c) {
        const bf16x8* wr = (const bf16x8*)((const bf16_t*)W + (size_t)(c * 16 + (lane & 15)) * 128);
        bf16x8 b0 = wr[0 * 4 + kk4];
        bf16x8 b1 = wr[1 * 4 + kk4];
        bf16x8 b2 = wr[2 * 4 + kk4];
        bf16x8 b3 = wr[3 * 4 + kk4];
        f32x4 acc = {0.f, 0.f, 0.f, 0.f};
        acc = __builtin_amdgcn_mfma_f32_16x16x32_bf16(a0, b0, acc, 0, 0, 0);
        acc = __builtin_amdgcn_mfma_f32_16x16x32_bf16(a1, b1, acc, 0, 0, 0);
        acc = __builtin_amdgcn_mfma_f32_16x16x32_bf16(a2, b2, acc, 0, 0, 0);
        acc = __builtin_amdgcn_mfma_f32_16x16x32_bf16(a3, b3, acc, 0, 0, 0);
        int gcol = c * 16 + ocol;
        #pragma unroll
        for (int j = 0; j < 4; ++j) {
            int row = r0 + orow + j;
            float v = acc[j] * dv[j];
            float vnb = __shfl_down(v, 1);
            if (((lane & 1) == 0) && row < n) {
                int pk = fp8x2_pack(v, vnb);
                XW8[(size_t)row * 64 + (gcol >> 1)] = (ushort_t)(pk & 0xffff);
            }
        }
    }
}

// ---------------- fused q/k/v/skip MFMA ----------------
// KV8 dword (idx = gcol>>1 within row of 64): bytes [k(2d), k(2d+1), v(2d), v(2d+1)] fp8 x SCL_KV
__global__ __launch_bounds__(256) void k_qkvs_mfma(const __hip_bfloat16* __restrict__ X,
                                                   const __hip_bfloat16* __restrict__ W4,
                                                   const float* __restrict__ bq, const float* __restrict__ bk,
                                                   const float* __restrict__ bv, const float* __restrict__ bs,
                                                   __hip_bfloat16* __restrict__ Cqb, uint* __restrict__ KV8,
                                                   __hip_bfloat16* __restrict__ Bb, int n) {
    int wave = threadIdx.x >> 6, lane = threadIdx.x & 63;
    int r0 = blockIdx.x * 64 + wave * 16;
    if (r0 >= n) return;
    int mrow = r0 + (lane & 15);
    if (mrow >= n) mrow = n - 1;
    int kk4 = lane >> 4;
    const bf16x8* xr = (const bf16x8*)((const bf16_t*)X + (size_t)mrow * 128);
    bf16x8 a0 = xr[0 * 4 + kk4];
    bf16x8 a1 = xr[1 * 4 + kk4];
    bf16x8 a2 = xr[2 * 4 + kk4];
    bf16x8 a3 = xr[3 * 4 + kk4];
    int orow = (lane >> 4) * 4;
    int ocol = lane & 15;
    float karr[32];
    #pragma unroll
    for (int m = 0; m < 4; ++m) {
        const bf16_t* Wm = (const bf16_t*)W4 + (size_t)m * 16384;
        const float* bias = (m == 0) ? bq : (m == 1) ? bk : (m == 2) ? bv : bs;
        #pragma unroll
        for (int c = 0; c < 8; ++c) {
            const bf16x8* wr = (const bf16x8*)(Wm + (size_t)(c * 16 + (lane & 15)) * 128);
            bf16x8 b0 = wr[0 * 4 + kk4];
            bf16x8 b1 = wr[1 * 4 + kk4];
            bf16x8 b2 = wr[2 * 4 + kk4];
            bf16x8 b3 = wr[3 * 4 + kk4];
            f32x4 acc = {0.f, 0.f, 0.f, 0.f};
            acc = __builtin_amdgcn_mfma_f32_16x16x32_bf16(a0, b0, acc, 0, 0, 0);
            acc = __builtin_amdgcn_mfma_f32_16x16x32_bf16(a1, b1, acc, 0, 0, 0);
            acc = __builtin_amdgcn_mfma_f32_16x16x32_bf16(a2, b2, acc, 0, 0, 0);
            acc = __builtin_amdgcn_mfma_f32_16x16x32_bf16(a3, b3, acc, 0, 0, 0);
            int gcol = c * 16 + ocol;
            float bb = bias[gcol];
            #pragma unroll
            for (int j = 0; j < 4; ++j) {
                int row = r0 + orow + j;
                float v = acc[j] + bb;
                if (m == 1) karr[c * 4 + j] = v * SCL_KV;
                if (m == 0) {
                    if (row < n) store_out(&Cqb[(size_t)row * 128 + gcol], v * (0.25f / SCL_KV));
                } else if (m == 2) {
                    float vv = v * SCL_KV;
                    float kk = karr[c * 4 + j];
                    float kn = __shfl_down(kk, 1);
                    float vn = __shfl_down(vv, 1);
                    if (((lane & 1) == 0) && row < n) {
                        int pkk = fp8x2_pack(kk, kn);
                        int pkv = fp8x2_pack(vv, vn);
                        uint u = ((uint)pkk & 0xffffu) | ((uint)pkv << 16);
                        KV8[(size_t)row * 64 + (gcol >> 1)] = u;
                    }
                } else if (m == 3) {
                    if (row < n) store_out(&Bb[(size_t)row * 128 + gcol], v);
                }
            }
        }
    }
}

// ---------------- GCN aggregation: 1 wave/node, fp8 payload, ping-pong prefetch ----------------
__device__ __forceinline__ void gcn_load8(const int* __restrict__ col, int i, const ushort_t* __restrict__ xw,
                                          int lane, uint (&u)[8]) {
    #pragma unroll
    for (int j = 0; j < 8; ++j) {
        int c = RFL(col[i + j]);
        u[j] = (uint)xw[(size_t)c * 64 + lane];
    }
}

__device__ __forceinline__ void gcn_proc8(const uint (&u)[8], float2& acc) {
    float sx = 0.f, sy = 0.f;
    #pragma unroll
    for (int j = 0; j < 8; ++j) {
        float2 x = fp8x2_unpack<false>(u[j]);
        sx += x.x;
        sy += x.y;
    }
    acc.x += sx;
    acc.y += sy;
}

__global__ __launch_bounds__(256) void k_gcn_agg(const ushort_t* __restrict__ xw, const int* __restrict__ off,
                                                 const int* __restrict__ col, const float* __restrict__ dinv,
                                                 const float* __restrict__ bias, __hip_bfloat162* __restrict__ y, int n) {
    int wid = RFL((int)((blockIdx.x * 256 + threadIdx.x) >> 6));
    int lane = threadIdx.x & 63;
    if (wid >= n) return;
    float di = dinv[wid] * (1.f / SCL_XW);
    float2 acc = fp8x2_unpack<false>((uint)xw[(size_t)wid * 64 + lane]);
    int i = RFL(off[wid]), i1 = RFL(off[wid + 1]);
    uint ua[8], ub[8];
    if (i + 8 <= i1) {
        gcn_load8(col, i, xw, lane, ua);
        while (true) {
            int inext = i + 8;
            bool more = (inext + 8 <= i1);
            if (more) gcn_load8(col, inext, xw, lane, ub);
            gcn_proc8(ua, acc);
            i = inext;
            if (!more) break;
            inext = i + 8;
            more = (inext + 8 <= i1);
            if (more) gcn_load8(col, inext, xw, lane, ua);
            gcn_proc8(ub, acc);
            i = inext;
            if (!more) break;
        }
    }
    for (; i < i1; ++i) {
        int c0 = RFL(col[i]);
        float2 x0 = fp8x2_unpack<false>((uint)xw[(size_t)c0 * 64 + lane]);
        acc.x += x0.x;
        acc.y += x0.y;
    }
    float2 b2 = ((const float2*)bias)[lane];
    __hip_bfloat162 o;
    o.x = __float2bfloat16(fmaxf(di * acc.x + b2.x, 0.f));
    o.y = __float2bfloat16(fmaxf(di * acc.y + b2.y, 0.f));
    y[(size_t)wid * 64 + lane] = o;
}

// ---------------- transformer attention: head-per-lane-group, 1 wave/dst ----------------
// lane = (h = lane>>3, j = lane&7). Lane holds all 16 q feats of head h, processes edge i+j.
// KV row = 64 dwords; head h occupies dwords [h*8, h*8+8), dword d = [k2d,k2d+1,v2d,v2d+1] fp8.
__device__ __forceinline__ void attn_chunk(uint4 A, uint4 Bv, bool act, const float (&qf)[16],
                                           float& m, float& s, float (&acc)[16]) {
    uint au[8] = {A.x, A.y, A.z, A.w, Bv.x, Bv.y, Bv.z, Bv.w};
    float l = 0.f;
    #pragma unroll
    for (int d = 0; d < 8; ++d) {
        float2 kk = fp8x2_unpack<false>(au[d]);
        l = fmaf(qf[2 * d], kk.x, l);
        l = fmaf(qf[2 * d + 1], kk.y, l);
    }
    if (!act) l = -INFINITY;
    float mx = l;
    mx = fmaxf(mx, __shfl_xor(mx, 1));
    mx = fmaxf(mx, __shfl_xor(mx, 2));
    mx = fmaxf(mx, __shfl_xor(mx, 4));
    if (mx > m) {
        float corr = __expf(m - mx);     // 0 on first real chunk (m=-inf)
        s *= corr;
        #pragma unroll
        for (int f = 0; f < 16; ++f) acc[f] *= corr;
        m = mx;
    }
    float e = act ? __expf(l - m) : 0.f;
    s += e;
    #pragma unroll
    for (int d = 0; d < 8; ++d) {
        float2 vv = fp8x2_unpack<true>(au[d]);
        acc[2 * d] = fmaf(e, vv.x, acc[2 * d]);
        acc[2 * d + 1] = fmaf(e, vv.y, acc[2 * d + 1]);
    }
}

__global__ __launch_bounds__(256) void k_attn(const uint* __restrict__ qb, const uint* __restrict__ kv8,
                                              const int* __restrict__ off, const int* __restrict__ col,
                                              uint* __restrict__ io, int n) {
    int wid = RFL((int)((blockIdx.x * 256 + threadIdx.x) >> 6));
    int lane = threadIdx.x & 63;
    int h = lane >> 3, j = lane & 7;
    if (wid >= n) return;
    float qf[16];
    {
        const uint4* q4 = (const uint4*)(qb + (size_t)wid * 64 + h * 8);
        uint4 qa = q4[0], qc = q4[1];
        uint qu[8] = {qa.x, qa.y, qa.z, qa.w, qc.x, qc.y, qc.z, qc.w};
        #pragma unroll
        for (int d = 0; d < 8; ++d) {
            float2 t = bf2_unpack(qu[d]);
            qf[2 * d] = t.x;
            qf[2 * d + 1] = t.y;
        }
    }
    float acc[16];
    #pragma unroll
    for (int f = 0; f < 16; ++f) acc[f] = 0.f;
    float m = -INFINITY, s = 0.f;
    int i = RFL(off[wid]), i1 = RFL(off[wid + 1]);
    uint4 A0, B0, A1, B1;
    bool act0 = false, act1 = false;
    if (i < i1) {
        {
            int idx = i + j; act0 = idx < i1;
            int c = col[act0 ? idx : (i1 - 1)];
            const uint4* pb = (const uint4*)(kv8 + ((size_t)(uint)c << 6) + (h << 3));
            A0 = pb[0]; B0 = pb[1];
        }
        while (true) {
            int inext = i + 8;
            bool more = inext < i1;
            if (more) {
                int idx = inext + j; act1 = idx < i1;
                int c = col[act1 ? idx : (i1 - 1)];
                const uint4* pb = (const uint4*)(kv8 + ((size_t)(uint)c << 6) + (h << 3));
                A1 = pb[0]; B1 = pb[1];
            }
            attn_chunk(A0, B0, act0, qf, m, s, acc);
            i = inext;
            if (!more) break;
            inext = i + 8;
            more = inext < i1;
            if (more) {
                int idx = inext + j; act0 = idx < i1;
                int c = col[act0 ? idx : (i1 - 1)];
                const uint4* pb = (const uint4*)(kv8 + ((size_t)(uint)c << 6) + (h << 3));
                A0 = pb[0]; B0 = pb[1];
            }
            attn_chunk(A1, B1, act1, qf, m, s, acc);
            i = inext;
            if (!more) break;
        }
    }
    // s total over the 8 edge-slot lanes of this head
    s += __shfl_xor(s, 1);
    s += __shfl_xor(s, 2);
    s += __shfl_xor(s, 4);
    // fold acc 16 -> 8 -> 4 -> 2; lane j ends with feats 2j, 2j+1 of head h
    float r8[8];
    #pragma unroll
    for (int f = 0; f < 8; ++f) {
        float send = (j & 4) ? acc[f] : acc[f + 8];
        float recv = __shfl_xor(send, 4);
        r8[f] = ((j & 4) ? acc[f + 8] : acc[f]) + recv;
    }
    float r4[4];
    #pragma unroll
    for (int f = 0; f < 4; ++f) {
        float send = (j & 2) ? r8[f] : r8[f + 4];
        float recv = __shfl_xor(send, 2);
        r4[f] = ((j & 2) ? r8[f + 4] : r8[f]) + recv;
    }
    float r2[2];
    #pragma unroll
    for (int f = 0; f < 2; ++f) {
        float send = (j & 1) ? r4[f] : r4[f + 2];
        float recv = __shfl_xor(send, 1);
        r2[f] = ((j & 1) ? r4[f + 2] : r4[f]) + recv;
    }
    float inv = (1.f / SCL_KV) / fmaxf(s, 1e-16f);
    uint* orow = io + (size_t)wid * 64 + lane;   // uint idx = h*8 + j
    float2 o2 = bf2_unpack(*orow);               // skip connection already there
    o2.x += r2[0] * inv;
    o2.y += r2[1] * inv;
    *orow = bf2_pack(o2.x, o2.y);
}

// ---------------- mean-pool per graph (batch sorted), bf16 in, 64 nodes/block ----------------
__global__ __launch_bounds__(128) void k_pool(const __hip_bfloat16* __restrict__ x, const int* __restrict__ batch,
                                              float* __restrict__ gsum, float* __restrict__ cnt, int n) {
    int t = threadIdx.x;
    int start = blockIdx.x * 64;
    int end = start + 64; if (end > n) end = n;
    if (start >= n) return;
    int cur = batch[start];
    float acc = 0.f;
    int run = 0;
    for (int nn = start; nn < end; ++nn) {
        int g = batch[nn];
        if (g != cur) {
            atomicAdd(&gsum[cur * 128 + t], acc);
            if (t == 0) atomicAdd(&cnt[cur], (float)run);
            acc = 0.f; run = 0; cur = g;
        }
        acc += __bfloat162float(x[(size_t)nn * 128 + t]);
        run++;
    }
    atomicAdd(&gsum[cur * 128 + t], acc);
    if (t == 0) atomicAdd(&cnt[cur], (float)run);
}

// ---------------- FiLM + LSTM + LayerNorm + dueling heads, one block per graph ----------------
__global__ __launch_bounds__(128) void k_final(
    const float* __restrict__ gsum, const float* __restrict__ cnt, const float* __restrict__ w,
    const float* __restrict__ Wgam, const float* __restrict__ bgam,
    const float* __restrict__ Wbet, const float* __restrict__ bbet,
    const float* __restrict__ hprev, const float* __restrict__ cprev,
    const float* __restrict__ Wih, const float* __restrict__ bih,
    const float* __restrict__ Whh, const float* __restrict__ bhh,
    const float* __restrict__ lng, const float* __restrict__ lnb,
    const float* __restrict__ Wa1, const float* __restrict__ ba1,
    const float* __restrict__ Wa2, const float* __restrict__ ba2,
    const float* __restrict__ Wv1, const float* __restrict__ bv1,
    const float* __restrict__ Wv2, const float* __restrict__ bv2,
    float* __restrict__ out_qv, float* __restrict__ out_h, float* __restrict__ out_c) {
    int g = blockIdx.x, t = threadIdx.x;
    __shared__ __align__(16) float ge[128], hp[128], hn[128], r1[128], a1s[128], red[128];
    __shared__ float adv[16], val[2], mu_s, var_s;

    float w0 = w[g * 2 + 0], w1 = w[g * 2 + 1];
    float c = fmaxf(cnt[g], 1.f);
    float mn = gsum[g * 128 + t] / c;
    float gam = w0 * Wgam[2 * t] + w1 * Wgam[2 * t + 1] + bgam[t];
    float bet = w0 * Wbet[2 * t] + w1 * Wbet[2 * t + 1] + bbet[t];
    ge[t] = (1.f + gam) * mn + bet;
    hp[t] = hprev[g * 128 + t];
    __syncthreads();

    float gi = bih[t] + bhh[t];
    float gf = bih[128 + t] + bhh[128 + t];
    float gg = bih[256 + t] + bhh[256 + t];
    float go = bih[384 + t] + bhh[384 + t];
    {
        const float4* ge4 = (const float4*)ge;
        const float4* hp4 = (const float4*)hp;
        const float4* Ai = (const float4*)(Wih + (size_t)t * 128);
        const float4* Af = (const float4*)(Wih + (size_t)(128 + t) * 128);
        const float4* Ag = (const float4*)(Wih + (size_t)(256 + t) * 128);
        const float4* Ao = (const float4*)(Wih + (size_t)(384 + t) * 128);
        const float4* Hi = (const float4*)(Whh + (size_t)t * 128);
        const float4* Hf = (const float4*)(Whh + (size_t)(128 + t) * 128);
        const float4* Hg = (const float4*)(Whh + (size_t)(256 + t) * 128);
        const float4* Ho = (const float4*)(Whh + (size_t)(384 + t) * 128);
        #pragma unroll 4
        for (int k4 = 0; k4 < 32; ++k4) {
            float4 a = ge4[k4], h4 = hp4[k4], u;
            u = Ai[k4]; gi += a.x * u.x + a.y * u.y + a.z * u.z + a.w * u.w;
            u = Hi[k4]; gi += h4.x * u.x + h4.y * u.y + h4.z * u.z + h4.w * u.w;
            u = Af[k4]; gf += a.x * u.x + a.y * u.y + a.z * u.z + a.w * u.w;
            u = Hf[k4]; gf += h4.x * u.x + h4.y * u.y + h4.z * u.z + h4.w * u.w;
            u = Ag[k4]; gg += a.x * u.x + a.y * u.y + a.z * u.z + a.w * u.w;
            u = Hg[k4]; gg += h4.x * u.x + h4.y * u.y + h4.z * u.z + h4.w * u.w;
            u = Ao[k4]; go += a.x * u.x + a.y * u.y + a.z * u.z + a.w * u.w;
            u = Ho[k4]; go += h4.x * u.x + h4.y * u.y + h4.z * u.z + h4.w * u.w;
        }
    }
    float ig = 1.f / (1.f + __expf(-gi));
    float fg = 1.f / (1.f + __expf(-gf));
    float gc = tanhf(gg);
    float og = 1.f / (1.f + __expf(-go));
    float craw = fg * cprev[g * 128 + t] + ig * gc;
    float hraw = og * tanhf(craw);
    out_c[g * 128 + t] = fminf(fmaxf(craw, -1e6f), 1e6f);

    red[t] = hraw;
    __syncthreads();
    for (int s2 = 64; s2 > 0; s2 >>= 1) { if (t < s2) red[t] += red[t + s2]; __syncthreads(); }
    if (t == 0) mu_s = red[0] * (1.f / 128.f);
    __syncthreads();
    float mu = mu_s;
    float d = hraw - mu;
    red[t] = d * d;
    __syncthreads();
    for (int s2 = 64; s2 > 0; s2 >>= 1) { if (t < s2) red[t] += red[t + s2]; __syncthreads(); }
    if (t == 0) var_s = red[0] * (1.f / 128.f);
    __syncthreads();
    float hv = d * rsqrtf(var_s + 1e-5f) * lng[t] + lnb[t];
    hn[t] = hv;
    out_h[g * 128 + t] = hv;
    __syncthreads();

    float accv = bv1[t], acca = ba1[t];
    {
        const float4* hn4 = (const float4*)hn;
        const float4* V1 = (const float4*)(Wv1 + (size_t)t * 128);
        const float4* A1 = (const float4*)(Wa1 + (size_t)t * 128);
        #pragma unroll 4
        for (int k4 = 0; k4 < 32; ++k4) {
            float4 hh = hn4[k4], u;
            u = V1[k4]; accv += hh.x * u.x + hh.y * u.y + hh.z * u.z + hh.w * u.w;
            u = A1[k4]; acca += hh.x * u.x + hh.y * u.y + hh.z * u.z + hh.w * u.w;
        }
    }
    r1[t] = fmaxf(accv, 0.f);
    a1s[t] = fmaxf(acca, 0.f);
    __syncthreads();
    if (t < 2) {
        float s = bv2[t];
        const float4* V2 = (const float4*)(Wv2 + (size_t)t * 128);
        const float4* r4 = (const float4*)r1;
        for (int k4 = 0; k4 < 32; ++k4) { float4 u = V2[k4], rr = r4[k4]; s += rr.x * u.x + rr.y * u.y + rr.z * u.z + rr.w * u.w; }
        val[t] = s;
    }
    if (t < 14) {
        float s = ba2[t];
        const float4* A2 = (const float4*)(Wa2 + (size_t)t * 128);
        const float4* a4 = (const float4*)a1s;
        for (int k4 = 0; k4 < 32; ++k4) { float4 u = A2[k4], aa = a4[k4]; s += aa.x * u.x + aa.y * u.y + aa.z * u.z + aa.w * u.w; }
        adv[t] = s;
    }
    __syncthreads();
    if (t < 14) {
        int o = t & 1;
        float mo = (adv[o] + adv[o + 2] + adv[o + 4] + adv[o + 6] + adv[o + 8] + adv[o + 10] + adv[o + 12]) * (1.f / 7.f);
        float qq = val[o] + adv[t] - mo;
        if (isnan(qq)) qq = 0.f;
        qq = fminf(fmaxf(qq, -100.f), 100.f);
        out_qv[g * 14 + t] = qq;
    }
}

extern "C" void kernel_launch(void* const* d_in, const int* in_sizes, int n_in,
                              void* d_out, int out_size, void* d_ws, size_t ws_size,
                              hipStream_t stream) {
    const float* nf    = (const float*)d_in[0];
    const int*   ei    = (const int*)d_in[1];
    const int*   batch = (const int*)d_in[2];
    const float* w     = (const float*)d_in[3];
    const float* hprev = (const float*)d_in[4];
    const float* cprev = (const float*)d_in[5];
    const float* W_emb = (const float*)d_in[6];  const float* b_emb = (const float*)d_in[7];
    const float* W_g1  = (const float*)d_in[8];  const float* b_g1  = (const float*)d_in[9];
    const float* W_g2  = (const float*)d_in[10]; const float* b_g2  = (const float*)d_in[11];
    const float* Wq    = (const float*)d_in[12]; const float* bq    = (const float*)d_in[13];
    const float* Wk    = (const float*)d_in[14]; const float* bk    = (const float*)d_in[15];
    const float* Wv    = (const float*)d_in[16]; const float* bv    = (const float*)d_in[17];
    const float* Wskip = (const float*)d_in[18]; const float* bskip = (const float*)d_in[19];
    const float* Wgam  = (const float*)d_in[20]; const float* bgam  = (const float*)d_in[21];
    const float* Wbet  = (const float*)d_in[22]; const float* bbet  = (const float*)d_in[23];
    const float* Wih   = (const float*)d_in[24]; const float* bih   = (const float*)d_in[25];
    const float* Whh   = (const float*)d_in[26]; const float* bhh   = (const float*)d_in[27];
    const float* lng   = (const float*)d_in[28]; const float* lnb   = (const float*)d_in[29];
    const float* Wa1   = (const float*)d_in[30]; const float* ba1   = (const float*)d_in[31];
    const float* Wa2   = (const float*)d_in[32]; const float* ba2   = (const float*)d_in[33];
    const float* Wv1   = (const float*)d_in[34]; const float* bv1   = (const float*)d_in[35];
    const float* Wv2   = (const float*)d_in[36]; const float* bv2   = (const float*)d_in[37];

    int N = in_sizes[2];
    int E = in_sizes[1] / 2;
    int B = in_sizes[4] / 128;
    int nbk = (N + 31) >> BK_SH;   // buckets of 32 dst nodes (<= 2048)

    char* p = (char*)d_ws;
    auto alloc = [&](size_t bytes) { char* r = p; p += (bytes + 511) & ~(size_t)511; return r; };
    int*   bcnt   = (int*)alloc((size_t)nbk * 4);
    int*   bcur   = (int*)alloc((size_t)nbk * 4);
    float* gsum   = (float*)alloc((size_t)B * 128 * 4);
    float* cnt    = (float*)alloc((size_t)B * 4);
    size_t zbytes = (size_t)(p - (char*)d_ws);   // region zeroed each call
    int*   boff   = (int*)alloc((size_t)(nbk + 1) * 4);
    uint2* pairs  = (uint2*)alloc((size_t)E * 8);
    int*   off    = (int*)alloc((size_t)(N + 1) * 4);
    int*   col    = (int*)alloc((size_t)E * 4);
    float* dinv   = (float*)alloc((size_t)N * 4);
    __hip_bfloat16* Wc  = (__hip_bfloat16*)alloc((size_t)6 * 16384 * 2);  // bf16 weights: g1,g2,q,k,v,skip
    __hip_bfloat16* X0b = (__hip_bfloat16*)alloc((size_t)N * 128 * 2);    // x0 / x2
    __hip_bfloat16* X1b = (__hip_bfloat16*)alloc((size_t)N * 128 * 2);    // x1
    ushort_t* XW8 = (ushort_t*)alloc((size_t)N * 128);                    // fp8 xw' (prescaled, x32)
    uint*  KV8 = (uint*)alloc((size_t)N * 256);                           // fp8 head-blocked [k,k,v,v] dwords (x16)
    __hip_bfloat16* Cqb = (__hip_bfloat16*)alloc((size_t)N * 128 * 2);    // q bf16 (x 0.25/16)
    __hip_bfloat16* Bb  = (__hip_bfloat16*)alloc((size_t)N * 128 * 2);    // skip + attn out, bf16
    if ((size_t)(p - (char*)d_ws) > ws_size) return;

    (void)hipMemsetAsync(d_ws, 0, zbytes, stream);

    const __hip_bfloat16* Wg1b  = Wc + 0 * 16384;
    const __hip_bfloat16* Wg2b  = Wc + 1 * 16384;
    const __hip_bfloat16* Wqkvs = Wc + 2 * 16384;   // q,k,v,skip contiguous
    k_cvt6<<<384, 256, 0, stream>>>(W_g1, W_g2, Wq, Wk, Wv, Wskip, Wc);

    int gC = (E + CHUNK - 1) / CHUNK;
    k_bcount<<<gC, 1024, 0, stream>>>(ei, bcnt, E, nbk);
    k_bscan<<<1, 1024, 0, stream>>>(bcnt, boff, nbk);
    k_bfill<<<gC, 1024, 0, stream>>>(ei, boff, bcur, pairs, E, nbk);
    k_bucket<<<nbk, 256, 0, stream>>>(pairs, boff, off, dinv, col, N, nbk, E);

    int gN = (N + 3) / 4;       // gather kernels: 4 waves/block, 1 node/wave
    int gM = (N + 63) / 64;     // MFMA kernels: 64 rows/block

    k_linear<32, true, true, __hip_bfloat16><<<2048, 256, 0, stream>>>(nf, W_emb, b_emb, X0b, N);   // x0 bf16
    k_lin_mfma_scale<<<gM, 256, 0, stream>>>(X0b, Wg1b, dinv, XW8, N);                              // xw1' fp8
    k_gcn_agg<<<gN, 256, 0, stream>>>(XW8, off, col, dinv, b_g1, (__hip_bfloat162*)X1b, N);         // x1
    k_lin_mfma_scale<<<gM, 256, 0, stream>>>(X1b, Wg2b, dinv, XW8, N);                              // xw2' fp8
    k_gcn_agg<<<gN, 256, 0, stream>>>(XW8, off, col, dinv, b_g2, (__hip_bfloat162*)X0b, N);         // x2

    k_qkvs_mfma<<<gM, 256, 0, stream>>>(X0b, Wqkvs, bq, bk, bv, bskip, Cqb, KV8, Bb, N);            // q,KV,skip
    k_attn<<<gN, 256, 0, stream>>>((const uint*)Cqb, KV8, off, col, (uint*)Bb, N);                  // Bb += attn

    k_pool<<<gM, 128, 0, stream>>>(Bb, batch, gsum, cnt, N);

    float* out_qv = (float*)d_out;
    float* out_h  = out_qv + (size_t)B * 14;
    float* out_c  = out_h + (size_t)B * 128;
    k_final<<<B, 128, 0, stream>>>(gsum, cnt, w, Wgam, bgam, Wbet, bbet, hprev, cprev,
                                   Wih, bih, Whh, bhh, lng, lnb,
                                   Wa1, ba1, Wa2, ba2, Wv1, bv1, Wv2, bv2,
                                   out_qv, out_h, out_c);
}

// Round 16
// 370.102 us; speedup vs baseline: 1.0128x; 1.0128x over previous
//
#include <hip/hip_runtime.h>
#include <hip/hip_bf16.h>
#include <math.h>

typedef unsigned int uint;
typedef unsigned short ushort_t;
typedef __bf16 bf16_t;
typedef bf16_t bf16x8 __attribute__((ext_vector_type(8)));
typedef float f32x4 __attribute__((ext_vector_type(4)));
typedef float f32x2 __attribute__((ext_vector_type(2)));

__device__ inline float2 bf2_unpack(uint u) {
    union { uint i; float f; } a, b;
    a.i = u << 16;
    b.i = u & 0xffff0000u;
    return make_float2(a.f, b.f);   // (lo, hi)
}

__device__ inline uint bf2_pack(float lo, float hi) {
    __hip_bfloat162 h;
    h.x = __float2bfloat16(lo);
    h.y = __float2bfloat16(hi);
    return *(uint*)&h;              // hi<<16 | lo
}

// fp8 e4m3 (OCP) pack/unpack via HW converts (word selector must be compile-time const)
template<bool WORD>
__device__ __forceinline__ float2 fp8x2_unpack(uint u) {
    f32x2 r = __builtin_amdgcn_cvt_pk_f32_fp8((int)u, WORD);
    return make_float2(r[0], r[1]);
}
__device__ __forceinline__ int fp8x2_pack(float a, float b) {
    return __builtin_amdgcn_cvt_pk_fp8_f32(a, b, 0, false);  // bytes [a,b] in low 16
}

__device__ inline void store_out(float* p, float v) { *p = v; }
__device__ inline void store_out(__hip_bfloat16* p, float v) { *p = __float2bfloat16(v); }

#define RFL(x) __builtin_amdgcn_readfirstlane(x)

#define SCL_XW 32.f
#define SCL_KV 16.f
#define BK_SH 5               // 32 dst nodes per bucket
#define CHUNK 16384           // edges per binning block

// ---------------- bucketed CSR build: LDS-histogram binning (low-contention) ----------------
__global__ __launch_bounds__(1024) void k_bcount(const int* __restrict__ ei, int* __restrict__ bcnt,
                                                 int E, int nbk) {
    __shared__ int hist[2048];
    int t = threadIdx.x;
    for (int i = t; i < nbk; i += 1024) hist[i] = 0;
    __syncthreads();
    int e0 = blockIdx.x * CHUNK;
    int e1 = e0 + CHUNK; if (e1 > E) e1 = E;
    for (int e = e0 + t; e < e1; e += 1024)
        atomicAdd(&hist[(uint)ei[E + e] >> BK_SH], 1);
    __syncthreads();
    for (int i = t; i < nbk; i += 1024) {
        int c = hist[i];
        if (c) atomicAdd(&bcnt[i], c);
    }
}

// single-block chunked exclusive scan over nbk buckets; boff[nbk] = E
__global__ __launch_bounds__(1024) void k_bscan(const int* __restrict__ bcnt, int* __restrict__ boff, int nbk) {
    __shared__ int tmp[1024];
    int t = threadIdx.x;
    int per = (nbk + 1023) >> 10;
    int s0 = t * per, s1 = s0 + per; if (s1 > nbk) s1 = nbk;
    int sum = 0;
    for (int i = s0; i < s1; ++i) sum += bcnt[i];
    tmp[t] = sum;
    __syncthreads();
    for (int d = 1; d < 1024; d <<= 1) {
        int a = (t >= d) ? tmp[t - d] : 0;
        __syncthreads();
        tmp[t] += a;
        __syncthreads();
    }
    int carry = tmp[t] - sum;
    for (int i = s0; i < s1; ++i) { boff[i] = carry; carry += bcnt[i]; }
    if (t == 1023) boff[nbk] = tmp[1023];
}

// binned scatter: per-block LDS histogram -> one reservation atomic per (block,bucket) -> run writes
__global__ __launch_bounds__(1024) void k_bfill(const int* __restrict__ ei, const int* __restrict__ boff,
                                                int* __restrict__ bcur, uint2* __restrict__ pairs,
                                                int E, int nbk) {
    __shared__ int hist[2048];
    __shared__ int basep[2048];
    int t = threadIdx.x;
    for (int i = t; i < nbk; i += 1024) hist[i] = 0;
    __syncthreads();
    int e0 = blockIdx.x * CHUNK;
    int e1 = e0 + CHUNK; if (e1 > E) e1 = E;
    for (int e = e0 + t; e < e1; e += 1024)
        atomicAdd(&hist[(uint)ei[E + e] >> BK_SH], 1);
    __syncthreads();
    for (int i = t; i < nbk; i += 1024) {
        int c = hist[i];
        basep[i] = c ? atomicAdd(&bcur[i], c) : 0;
        hist[i] = 0;                                   // reuse as local cursor
    }
    __syncthreads();
    for (int e = e0 + t; e < e1; e += 1024) {
        int d = ei[E + e];
        int s = ei[e];
        int b = (uint)d >> BK_SH;
        int p = atomicAdd(&hist[b], 1);                // LDS cursor
        pairs[boff[b] + basep[b] + p] = make_uint2((uint)d, (uint)s);
    }
}

// one block per bucket: LDS per-dst count + scan -> off/dinv; then local scatter of col
__global__ __launch_bounds__(256) void k_bucket(const uint2* __restrict__ pairs, const int* __restrict__ boff,
                                                int* __restrict__ off, float* __restrict__ dinv,
                                                int* __restrict__ col, int N, int nbk, int E) {
    int b = blockIdx.x, t = threadIdx.x;
    __shared__ int cnt[32], excl[32], cur[32];
    int base = boff[b], end = boff[b + 1];
    if (t < 32) cnt[t] = 0;
    __syncthreads();
    for (int i = base + t; i < end; i += 256) {
        uint2 p = pairs[i];
        atomicAdd(&cnt[p.x & 31], 1);
    }
    __syncthreads();
    if (t == 0) {
        int run = base;
        #pragma unroll
        for (int j = 0; j < 32; ++j) { excl[j] = run; cur[j] = run; run += cnt[j]; }
    }
    __syncthreads();
    if (t < 32) {
        int node = (b << BK_SH) + t;
        if (node < N) {
            off[node] = excl[t];
            dinv[node] = rsqrtf((float)(cnt[t] + 1));   // self-loop adds 1
        }
    }
    if (b == nbk - 1 && t == 0) off[N] = E;
    for (int i = base + t; i < end; i += 256) {
        uint2 p = pairs[i];
        int pos = atomicAdd(&cur[p.x & 31], 1);
        col[pos] = (int)p.y;
    }
}

// ---------------- fp32 -> bf16 weight conversion (6 x 128x128 mats) ----------------
__global__ __launch_bounds__(256) void k_cvt6(const float* __restrict__ s0, const float* __restrict__ s1,
                                              const float* __restrict__ s2, const float* __restrict__ s3,
                                              const float* __restrict__ s4, const float* __restrict__ s5,
                                              __hip_bfloat16* __restrict__ dst) {
    int i = blockIdx.x * 256 + threadIdx.x;
    if (i >= 6 * 16384) return;
    int m = i >> 14;
    const float* s = (m == 0) ? s0 : (m == 1) ? s1 : (m == 2) ? s2 : (m == 3) ? s3 : (m == 4) ? s4 : s5;
    dst[i] = __float2bfloat16(s[i & 16383]);
}

// ---------------- scalar linear for FI=32 (embed), bf16 out ----------------
template<int FI, bool BIAS, bool RELU, typename OUT>
__global__ __launch_bounds__(256) void k_linear(const float* __restrict__ x, const float* __restrict__ W,
                                                const float* __restrict__ b, OUT* __restrict__ y, int n) {
    __shared__ float4 Wt4[(FI / 4) * 128];
    __shared__ float4 xl[2][FI / 4];
    int t = threadIdx.x & 127;
    int h = threadIdx.x >> 7;
    {
        const float4* Wrow = (const float4*)(W + (size_t)t * FI);
        #pragma unroll
        for (int k4 = h * (FI / 8); k4 < (h + 1) * (FI / 8); ++k4) Wt4[k4 * 128 + t] = Wrow[k4];
    }
    float bias = 0.f;
    if (BIAS) bias = b[t];
    __syncthreads();
    for (int n0 = blockIdx.x * 2; n0 < n; n0 += gridDim.x * 2) {
        int nn = n0 + h;
        if (nn < n && t < FI / 4) xl[h][t] = ((const float4*)(x + (size_t)nn * FI))[t];
        __syncthreads();
        if (nn < n) {
            float acc = bias;
            #pragma unroll
            for (int k4 = 0; k4 < FI / 4; ++k4) {
                float4 xv = xl[h][k4];
                float4 wv = Wt4[k4 * 128 + t];
                acc += xv.x * wv.x + xv.y * wv.y + xv.z * wv.z + xv.w * wv.w;
            }
            if (RELU) acc = fmaxf(acc, 0.f);
            store_out(&y[(size_t)nn * 128 + t], acc);
        }
        __syncthreads();
    }
}

// ---------------- MFMA linear with per-row dinv prescale, fp8 x SCL_XW output ----------------
__global__ __launch_bounds__(256) void k_lin_mfma_scale(const __hip_bfloat16* __restrict__ X,
                                                        const __hip_bfloat16* __restrict__ W,
                                                        const float* __restrict__ dinv,
                                                        ushort_t* __restrict__ XW8, int n) {
    int wave = threadIdx.x >> 6, lane = threadIdx.x & 63;
    int r0 = blockIdx.x * 64 + wave * 16;
    if (r0 >= n) return;
    int mrow = r0 + (lane & 15);
    if (mrow >= n) mrow = n - 1;
    int kk4 = lane >> 4;
    const bf16x8* xr = (const bf16x8*)((const bf16_t*)X + (size_t)mrow * 128);
    bf16x8 a0 = xr[0 * 4 + kk4];
    bf16x8 a1 = xr[1 * 4 + kk4];
    bf16x8 a2 = xr[2 * 4 + kk4];
    bf16x8 a3 = xr[3 * 4 + kk4];
    int orow = (lane >> 4) * 4;
    int ocol = lane & 15;
    float dv[4];
    #pragma unroll
    for (int j = 0; j < 4; ++j) {
        int row = r0 + orow + j;
        dv[j] = ((row < n) ? dinv[row] : 0.f) * SCL_XW;
    }
    #pragma unroll
    for (int c = 0; c < 8; ++c) {
        const bf16x8* wr = (const bf16x8*)((const bf16_t*)W + (size_t)(c * 16 + (lane & 15)) * 128);
        bf16x8 b0 = wr[0 * 4 + kk4];
        bf16x8 b1 = wr[1 * 4 + kk4];
        bf16x8 b2 = wr[2 * 4 + kk4];
        bf16x8 b3 = wr[3 * 4 + kk4];
        f32x4 acc = {0.f, 0.f, 0.f, 0.f};
        acc = __builtin_amdgcn_mfma_f32_16x16x32_bf16(a0, b0, acc, 0, 0, 0);
        acc = __builtin_amdgcn_mfma_f32_16x16x32_bf16(a1, b1, acc, 0, 0, 0);
        acc = __builtin_amdgcn_mfma_f32_16x16x32_bf16(a2, b2, acc, 0, 0, 0);
        acc = __builtin_amdgcn_mfma_f32_16x16x32_bf16(a3, b3, acc, 0, 0, 0);
        int gcol = c * 16 + ocol;
        #pragma unroll
        for (int j = 0; j < 4; ++j) {
            int row = r0 + orow + j;
            float v = acc[j] * dv[j];
            float vnb = __shfl_down(v, 1);
            if (((lane & 1) == 0) && row < n) {
                int pk = fp8x2_pack(v, vnb);
                XW8[(size_t)row * 64 + (gcol >> 1)] = (ushort_t)(pk & 0xffff);
            }
        }
    }
}

// ---------------- fused q/k/v/skip MFMA ----------------
// KV8 dword (idx = gcol>>1 within row of 64): bytes [k(2d), k(2d+1), v(2d), v(2d+1)] fp8 x SCL_KV
__global__ __launch_bounds__(256) void k_qkvs_mfma(const __hip_bfloat16* __restrict__ X,
                                                   const __hip_bfloat16* __restrict__ W4,
                                                   const float* __restrict__ bq, const float* __restrict__ bk,
                                                   const float* __restrict__ bv, const float* __restrict__ bs,
                                                   __hip_bfloat16* __restrict__ Cqb, uint* __restrict__ KV8,
                                                   __hip_bfloat16* __restrict__ Bb, int n) {
    int wave = threadIdx.x >> 6, lane = threadIdx.x & 63;
    int r0 = blockIdx.x * 64 + wave * 16;
    if (r0 >= n) return;
    int mrow = r0 + (lane & 15);
    if (mrow >= n) mrow = n - 1;
    int kk4 = lane >> 4;
    const bf16x8* xr = (const bf16x8*)((const bf16_t*)X + (size_t)mrow * 128);
    bf16x8 a0 = xr[0 * 4 + kk4];
    bf16x8 a1 = xr[1 * 4 + kk4];
    bf16x8 a2 = xr[2 * 4 + kk4];
    bf16x8 a3 = xr[3 * 4 + kk4];
    int orow = (lane >> 4) * 4;
    int ocol = lane & 15;
    float karr[32];
    #pragma unroll
    for (int m = 0; m < 4; ++m) {
        const bf16_t* Wm = (const bf16_t*)W4 + (size_t)m * 16384;
        const float* bias = (m == 0) ? bq : (m == 1) ? bk : (m == 2) ? bv : bs;
        #pragma unroll
        for (int c = 0; c < 8; ++c) {
            const bf16x8* wr = (const bf16x8*)(Wm + (size_t)(c * 16 + (lane & 15)) * 128);
            bf16x8 b0 = wr[0 * 4 + kk4];
            bf16x8 b1 = wr[1 * 4 + kk4];
            bf16x8 b2 = wr[2 * 4 + kk4];
            bf16x8 b3 = wr[3 * 4 + kk4];
            f32x4 acc = {0.f, 0.f, 0.f, 0.f};
            acc = __builtin_amdgcn_mfma_f32_16x16x32_bf16(a0, b0, acc, 0, 0, 0);
            acc = __builtin_amdgcn_mfma_f32_16x16x32_bf16(a1, b1, acc, 0, 0, 0);
            acc = __builtin_amdgcn_mfma_f32_16x16x32_bf16(a2, b2, acc, 0, 0, 0);
            acc = __builtin_amdgcn_mfma_f32_16x16x32_bf16(a3, b3, acc, 0, 0, 0);
            int gcol = c * 16 + ocol;
            float bb = bias[gcol];
            #pragma unroll
            for (int j = 0; j < 4; ++j) {
                int row = r0 + orow + j;
                float v = acc[j] + bb;
                if (m == 1) karr[c * 4 + j] = v * SCL_KV;
                if (m == 0) {
                    if (row < n) store_out(&Cqb[(size_t)row * 128 + gcol], v * (0.25f / SCL_KV));
                } else if (m == 2) {
                    float vv = v * SCL_KV;
                    float kk = karr[c * 4 + j];
                    float kn = __shfl_down(kk, 1);
                    float vn = __shfl_down(vv, 1);
                    if (((lane & 1) == 0) && row < n) {
                        int pkk = fp8x2_pack(kk, kn);
                        int pkv = fp8x2_pack(vv, vn);
                        uint u = ((uint)pkk & 0xffffu) | ((uint)pkv << 16);
                        KV8[(size_t)row * 64 + (gcol >> 1)] = u;
                    }
                } else if (m == 3) {
                    if (row < n) store_out(&Bb[(size_t)row * 128 + gcol], v);
                }
            }
        }
    }
}

// ---------------- GCN aggregation: 1 wave/node, fp8 payload, 3-stage pipeline ----------------
__device__ __forceinline__ void gcn_cols(const int* __restrict__ col, int i, int (&c)[8]) {
    #pragma unroll
    for (int j = 0; j < 8; ++j) c[j] = RFL(col[i + j]);
}

__device__ __forceinline__ void gcn_issue(const ushort_t* __restrict__ xw, int lane,
                                          const int (&c)[8], uint (&u)[8]) {
    #pragma unroll
    for (int j = 0; j < 8; ++j) u[j] = (uint)xw[(size_t)c[j] * 64 + lane];
}

__device__ __forceinline__ void gcn_proc8(const uint (&u)[8], float2& acc) {
    float sx = 0.f, sy = 0.f;
    #pragma unroll
    for (int j = 0; j < 8; ++j) {
        float2 x = fp8x2_unpack<false>(u[j]);
        sx += x.x;
        sy += x.y;
    }
    acc.x += sx;
    acc.y += sy;
}

__global__ __launch_bounds__(256) void k_gcn_agg(const ushort_t* __restrict__ xw, const int* __restrict__ off,
                                                 const int* __restrict__ col, const float* __restrict__ dinv,
                                                 const float* __restrict__ bias, __hip_bfloat162* __restrict__ y, int n) {
    int wid = RFL((int)((blockIdx.x * 256 + threadIdx.x) >> 6));
    int lane = threadIdx.x & 63;
    if (wid >= n) return;
    float di = dinv[wid] * (1.f / SCL_XW);
    float2 acc = fp8x2_unpack<false>((uint)xw[(size_t)wid * 64 + lane]);
    int i = RFL(off[wid]), i1 = RFL(off[wid + 1]);
    int nfull = (i1 - i) >> 3;
    if (nfull > 0) {
        int cA[8], cB[8];
        uint ua[8], ub[8];
        gcn_cols(col, i, cA);            // cols chunk 0
        gcn_issue(xw, lane, cA, ua);     // data chunk 0
        if (nfull > 1) gcn_cols(col, i + 8, cB);
        int t = 0;
        while (true) {
            bool hasN = (t + 1 < nfull);
            if (hasN) gcn_issue(xw, lane, cB, ub);
            if (t + 2 < nfull) gcn_cols(col, i + 8 * (t + 2), cA);
            gcn_proc8(ua, acc);
            ++t; if (!hasN) break;
            hasN = (t + 1 < nfull);
            if (hasN) gcn_issue(xw, lane, cA, ua);
            if (t + 2 < nfull) gcn_cols(col, i + 8 * (t + 2), cB);
            gcn_proc8(ub, acc);
            ++t; if (!hasN) break;
        }
        i += nfull * 8;
    }
    for (; i < i1; ++i) {
        int c0 = RFL(col[i]);
        float2 x0 = fp8x2_unpack<false>((uint)xw[(size_t)c0 * 64 + lane]);
        acc.x += x0.x;
        acc.y += x0.y;
    }
    float2 b2 = ((const float2*)bias)[lane];
    __hip_bfloat162 o;
    o.x = __float2bfloat16(fmaxf(di * acc.x + b2.x, 0.f));
    o.y = __float2bfloat16(fmaxf(di * acc.y + b2.y, 0.f));
    y[(size_t)wid * 64 + lane] = o;
}

// ---------------- transformer attention: head-per-lane-group, 3-stage pipeline ----------------
// lane = (h = lane>>3, j = lane&7). Lane holds all 16 q feats of head h, processes edge i+j.
// KV row = 64 dwords; head h occupies dwords [h*8, h*8+8), dword d = [k2d,k2d+1,v2d,v2d+1] fp8.
__device__ __forceinline__ void attn_chunk(uint4 A, uint4 Bv, bool act, const float (&qf)[16],
                                           float& m, float& s, float (&acc)[16]) {
    uint au[8] = {A.x, A.y, A.z, A.w, Bv.x, Bv.y, Bv.z, Bv.w};
    float l = 0.f;
    #pragma unroll
    for (int d = 0; d < 8; ++d) {
        float2 kk = fp8x2_unpack<false>(au[d]);
        l = fmaf(qf[2 * d], kk.x, l);
        l = fmaf(qf[2 * d + 1], kk.y, l);
    }
    if (!act) l = -INFINITY;
    float mx = l;
    mx = fmaxf(mx, __shfl_xor(mx, 1));
    mx = fmaxf(mx, __shfl_xor(mx, 2));
    mx = fmaxf(mx, __shfl_xor(mx, 4));
    if (mx > m) {
        float corr = __expf(m - mx);     // 0 on first real chunk (m=-inf)
        s *= corr;
        #pragma unroll
        for (int f = 0; f < 16; ++f) acc[f] *= corr;
        m = mx;
    }
    float e = act ? __expf(l - m) : 0.f;
    s += e;
    #pragma unroll
    for (int d = 0; d < 8; ++d) {
        float2 vv = fp8x2_unpack<true>(au[d]);
        acc[2 * d] = fmaf(e, vv.x, acc[2 * d]);
        acc[2 * d + 1] = fmaf(e, vv.y, acc[2 * d + 1]);
    }
}

__global__ __launch_bounds__(256) void k_attn(const uint* __restrict__ qb, const uint* __restrict__ kv8,
                                              const int* __restrict__ off, const int* __restrict__ col,
                                              uint* __restrict__ io, int n) {
    int wid = RFL((int)((blockIdx.x * 256 + threadIdx.x) >> 6));
    int lane = threadIdx.x & 63;
    int h = lane >> 3, j = lane & 7;
    if (wid >= n) return;
    float qf[16];
    {
        const uint4* q4 = (const uint4*)(qb + (size_t)wid * 64 + h * 8);
        uint4 qa = q4[0], qc = q4[1];
        uint qu[8] = {qa.x, qa.y, qa.z, qa.w, qc.x, qc.y, qc.z, qc.w};
        #pragma unroll
        for (int d = 0; d < 8; ++d) {
            float2 t = bf2_unpack(qu[d]);
            qf[2 * d] = t.x;
            qf[2 * d + 1] = t.y;
        }
    }
    float acc[16];
    #pragma unroll
    for (int f = 0; f < 16; ++f) acc[f] = 0.f;
    float m = -INFINITY, s = 0.f;
    int i0 = RFL(off[wid]), i1 = RFL(off[wid + 1]);
    int nch = (i1 - i0 + 7) >> 3;   // masked 8-edge chunks
    if (nch > 0) {
        bool actA, actB = false, okA, okB = false;
        int colA, colB = 0;
        uint4 KA0, KA1, KB0, KB1;
        {
            int idx = i0 + j; actA = idx < i1;
            colA = col[actA ? idx : (i1 - 1)];
        }
        {
            const uint4* pb = (const uint4*)(kv8 + ((size_t)(uint)colA << 6) + (h << 3));
            KA0 = pb[0]; KA1 = pb[1]; okA = actA;
        }
        if (nch > 1) {
            int idx = i0 + 8 + j; actB = idx < i1;
            colB = col[actB ? idx : (i1 - 1)];
        }
        int t = 0;
        while (true) {
            bool hasN = (t + 1 < nch);
            if (hasN) {
                const uint4* pb = (const uint4*)(kv8 + ((size_t)(uint)colB << 6) + (h << 3));
                KB0 = pb[0]; KB1 = pb[1]; okB = actB;
            }
            if (t + 2 < nch) {
                int idx = i0 + 8 * (t + 2) + j; actA = idx < i1;
                colA = col[actA ? idx : (i1 - 1)];
            }
            attn_chunk(KA0, KA1, okA, qf, m, s, acc);
            ++t; if (!hasN) break;
            hasN = (t + 1 < nch);
            if (hasN) {
                const uint4* pb = (const uint4*)(kv8 + ((size_t)(uint)colA << 6) + (h << 3));
                KA0 = pb[0]; KA1 = pb[1]; okA = actA;
            }
            if (t + 2 < nch) {
                int idx = i0 + 8 * (t + 2) + j; actB = idx < i1;
                colB = col[actB ? idx : (i1 - 1)];
            }
            attn_chunk(KB0, KB1, okB, qf, m, s, acc);
            ++t; if (!hasN) break;
        }
    }
    // s total over the 8 edge-slot lanes of this head
    s += __shfl_xor(s, 1);
    s += __shfl_xor(s, 2);
    s += __shfl_xor(s, 4);
    // fold acc 16 -> 8 -> 4 -> 2; lane j ends with feats 2j, 2j+1 of head h
    float r8[8];
    #pragma unroll
    for (int f = 0; f < 8; ++f) {
        float send = (j & 4) ? acc[f] : acc[f + 8];
        float recv = __shfl_xor(send, 4);
        r8[f] = ((j & 4) ? acc[f + 8] : acc[f]) + recv;
    }
    float r4[4];
    #pragma unroll
    for (int f = 0; f < 4; ++f) {
        float send = (j & 2) ? r8[f] : r8[f + 4];
        float recv = __shfl_xor(send, 2);
        r4[f] = ((j & 2) ? r8[f + 4] : r8[f]) + recv;
    }
    float r2[2];
    #pragma unroll
    for (int f = 0; f < 2; ++f) {
        float send = (j & 1) ? r4[f] : r4[f + 2];
        float recv = __shfl_xor(send, 1);
        r2[f] = ((j & 1) ? r4[f + 2] : r4[f]) + recv;
    }
    float inv = (1.f / SCL_KV) / fmaxf(s, 1e-16f);
    uint* orow = io + (size_t)wid * 64 + lane;   // uint idx = h*8 + j
    float2 o2 = bf2_unpack(*orow);               // skip connection already there
    o2.x += r2[0] * inv;
    o2.y += r2[1] * inv;
    *orow = bf2_pack(o2.x, o2.y);
}

// ---------------- mean-pool per graph (batch sorted), bf16 in, 64 nodes/block ----------------
__global__ __launch_bounds__(128) void k_pool(const __hip_bfloat16* __restrict__ x, const int* __restrict__ batch,
                                              float* __restrict__ gsum, float* __restrict__ cnt, int n) {
    int t = threadIdx.x;
    int start = blockIdx.x * 64;
    int end = start + 64; if (end > n) end = n;
    if (start >= n) return;
    int cur = batch[start];
    float acc = 0.f;
    int run = 0;
    for (int nn = start; nn < end; ++nn) {
        int g = batch[nn];
        if (g != cur) {
            atomicAdd(&gsum[cur * 128 + t], acc);
            if (t == 0) atomicAdd(&cnt[cur], (float)run);
            acc = 0.f; run = 0; cur = g;
        }
        acc += __bfloat162float(x[(size_t)nn * 128 + t]);
        run++;
    }
    atomicAdd(&gsum[cur * 128 + t], acc);
    if (t == 0) atomicAdd(&cnt[cur], (float)run);
}

// ---------------- FiLM + LSTM + LayerNorm + dueling heads, one block per graph ----------------
__global__ __launch_bounds__(128) void k_final(
    const float* __restrict__ gsum, const float* __restrict__ cnt, const float* __restrict__ w,
    const float* __restrict__ Wgam, const float* __restrict__ bgam,
    const float* __restrict__ Wbet, const float* __restrict__ bbet,
    const float* __restrict__ hprev, const float* __restrict__ cprev,
    const float* __restrict__ Wih, const float* __restrict__ bih,
    const float* __restrict__ Whh, const float* __restrict__ bhh,
    const float* __restrict__ lng, const float* __restrict__ lnb,
    const float* __restrict__ Wa1, const float* __restrict__ ba1,
    const float* __restrict__ Wa2, const float* __restrict__ ba2,
    const float* __restrict__ Wv1, const float* __restrict__ bv1,
    const float* __restrict__ Wv2, const float* __restrict__ bv2,
    float* __restrict__ out_qv, float* __restrict__ out_h, float* __restrict__ out_c) {
    int g = blockIdx.x, t = threadIdx.x;
    __shared__ __align__(16) float ge[128], hp[128], hn[128], r1[128], a1s[128], red[128];
    __shared__ float adv[16], val[2], mu_s, var_s;

    float w0 = w[g * 2 + 0], w1 = w[g * 2 + 1];
    float c = fmaxf(cnt[g], 1.f);
    float mn = gsum[g * 128 + t] / c;
    float gam = w0 * Wgam[2 * t] + w1 * Wgam[2 * t + 1] + bgam[t];
    float bet = w0 * Wbet[2 * t] + w1 * Wbet[2 * t + 1] + bbet[t];
    ge[t] = (1.f + gam) * mn + bet;
    hp[t] = hprev[g * 128 + t];
    __syncthreads();

    float gi = bih[t] + bhh[t];
    float gf = bih[128 + t] + bhh[128 + t];
    float gg = bih[256 + t] + bhh[256 + t];
    float go = bih[384 + t] + bhh[384 + t];
    {
        const float4* ge4 = (const float4*)ge;
        const float4* hp4 = (const float4*)hp;
        const float4* Ai = (const float4*)(Wih + (size_t)t * 128);
        const float4* Af = (const float4*)(Wih + (size_t)(128 + t) * 128);
        const float4* Ag = (const float4*)(Wih + (size_t)(256 + t) * 128);
        const float4* Ao = (const float4*)(Wih + (size_t)(384 + t) * 128);
        const float4* Hi = (const float4*)(Whh + (size_t)t * 128);
        const float4* Hf = (const float4*)(Whh + (size_t)(128 + t) * 128);
        const float4* Hg = (const float4*)(Whh + (size_t)(256 + t) * 128);
        const float4* Ho = (const float4*)(Whh + (size_t)(384 + t) * 128);
        #pragma unroll 4
        for (int k4 = 0; k4 < 32; ++k4) {
            float4 a = ge4[k4], h4 = hp4[k4], u;
            u = Ai[k4]; gi += a.x * u.x + a.y * u.y + a.z * u.z + a.w * u.w;
            u = Hi[k4]; gi += h4.x * u.x + h4.y * u.y + h4.z * u.z + h4.w * u.w;
            u = Af[k4]; gf += a.x * u.x + a.y * u.y + a.z * u.z + a.w * u.w;
            u = Hf[k4]; gf += h4.x * u.x + h4.y * u.y + h4.z * u.z + h4.w * u.w;
            u = Ag[k4]; gg += a.x * u.x + a.y * u.y + a.z * u.z + a.w * u.w;
            u = Hg[k4]; gg += h4.x * u.x + h4.y * u.y + h4.z * u.z + h4.w * u.w;
            u = Ao[k4]; go += a.x * u.x + a.y * u.y + a.z * u.z + a.w * u.w;
            u = Ho[k4]; go += h4.x * u.x + h4.y * u.y + h4.z * u.z + h4.w * u.w;
        }
    }
    float ig = 1.f / (1.f + __expf(-gi));
    float fg = 1.f / (1.f + __expf(-gf));
    float gc = tanhf(gg);
    float og = 1.f / (1.f + __expf(-go));
    float craw = fg * cprev[g * 128 + t] + ig * gc;
    float hraw = og * tanhf(craw);
    out_c[g * 128 + t] = fminf(fmaxf(craw, -1e6f), 1e6f);

    red[t] = hraw;
    __syncthreads();
    for (int s2 = 64; s2 > 0; s2 >>= 1) { if (t < s2) red[t] += red[t + s2]; __syncthreads(); }
    if (t == 0) mu_s = red[0] * (1.f / 128.f);
    __syncthreads();
    float mu = mu_s;
    float d = hraw - mu;
    red[t] = d * d;
    __syncthreads();
    for (int s2 = 64; s2 > 0; s2 >>= 1) { if (t < s2) red[t] += red[t + s2]; __syncthreads(); }
    if (t == 0) var_s = red[0] * (1.f / 128.f);
    __syncthreads();
    float hv = d * rsqrtf(var_s + 1e-5f) * lng[t] + lnb[t];
    hn[t] = hv;
    out_h[g * 128 + t] = hv;
    __syncthreads();

    float accv = bv1[t], acca = ba1[t];
    {
        const float4* hn4 = (const float4*)hn;
        const float4* V1 = (const float4*)(Wv1 + (size_t)t * 128);
        const float4* A1 = (const float4*)(Wa1 + (size_t)t * 128);
        #pragma unroll 4
        for (int k4 = 0; k4 < 32; ++k4) {
            float4 hh = hn4[k4], u;
            u = V1[k4]; accv += hh.x * u.x + hh.y * u.y + hh.z * u.z + hh.w * u.w;
            u = A1[k4]; acca += hh.x * u.x + hh.y * u.y + hh.z * u.z + hh.w * u.w;
        }
    }
    r1[t] = fmaxf(accv, 0.f);
    a1s[t] = fmaxf(acca, 0.f);
    __syncthreads();
    if (t < 2) {
        float s = bv2[t];
        const float4* V2 = (const float4*)(Wv2 + (size_t)t * 128);
        const float4* r4 = (const float4*)r1;
        for (int k4 = 0; k4 < 32; ++k4) { float4 u = V2[k4], rr = r4[k4]; s += rr.x * u.x + rr.y * u.y + rr.z * u.z + rr.w * u.w; }
        val[t] = s;
    }
    if (t < 14) {
        float s = ba2[t];
        const float4* A2 = (const float4*)(Wa2 + (size_t)t * 128);
        const float4* a4 = (const float4*)a1s;
        for (int k4 = 0; k4 < 32; ++k4) { float4 u = A2[k4], aa = a4[k4]; s += aa.x * u.x + aa.y * u.y + aa.z * u.z + aa.w * u.w; }
        adv[t] = s;
    }
    __syncthreads();
    if (t < 14) {
        int o = t & 1;
        float mo = (adv[o] + adv[o + 2] + adv[o + 4] + adv[o + 6] + adv[o + 8] + adv[o + 10] + adv[o + 12]) * (1.f / 7.f);
        float qq = val[o] + adv[t] - mo;
        if (isnan(qq)) qq = 0.f;
        qq = fminf(fmaxf(qq, -100.f), 100.f);
        out_qv[g * 14 + t] = qq;
    }
}

extern "C" void kernel_launch(void* const* d_in, const int* in_sizes, int n_in,
                              void* d_out, int out_size, void* d_ws, size_t ws_size,
                              hipStream_t stream) {
    const float* nf    = (const float*)d_in[0];
    const int*   ei    = (const int*)d_in[1];
    const int*   batch = (const int*)d_in[2];
    const float* w     = (const float*)d_in[3];
    const float* hprev = (const float*)d_in[4];
    const float* cprev = (const float*)d_in[5];
    const float* W_emb = (const float*)d_in[6];  const float* b_emb = (const float*)d_in[7];
    const float* W_g1  = (const float*)d_in[8];  const float* b_g1  = (const float*)d_in[9];
    const float* W_g2  = (const float*)d_in[10]; const float* b_g2  = (const float*)d_in[11];
    const float* Wq    = (const float*)d_in[12]; const float* bq    = (const float*)d_in[13];
    const float* Wk    = (const float*)d_in[14]; const float* bk    = (const float*)d_in[15];
    const float* Wv    = (const float*)d_in[16]; const float* bv    = (const float*)d_in[17];
    const float* Wskip = (const float*)d_in[18]; const float* bskip = (const float*)d_in[19];
    const float* Wgam  = (const float*)d_in[20]; const float* bgam  = (const float*)d_in[21];
    const float* Wbet  = (const float*)d_in[22]; const float* bbet  = (const float*)d_in[23];
    const float* Wih   = (const float*)d_in[24]; const float* bih   = (const float*)d_in[25];
    const float* Whh   = (const float*)d_in[26]; const float* bhh   = (const float*)d_in[27];
    const float* lng   = (const float*)d_in[28]; const float* lnb   = (const float*)d_in[29];
    const float* Wa1   = (const float*)d_in[30]; const float* ba1   = (const float*)d_in[31];
    const float* Wa2   = (const float*)d_in[32]; const float* ba2   = (const float*)d_in[33];
    const float* Wv1   = (const float*)d_in[34]; const float* bv1   = (const float*)d_in[35];
    const float* Wv2   = (const float*)d_in[36]; const float* bv2   = (const float*)d_in[37];

    int N = in_sizes[2];
    int E = in_sizes[1] / 2;
    int B = in_sizes[4] / 128;
    int nbk = (N + 31) >> BK_SH;   // buckets of 32 dst nodes (<= 2048)

    char* p = (char*)d_ws;
    auto alloc = [&](size_t bytes) { char* r = p; p += (bytes + 511) & ~(size_t)511; return r; };
    int*   bcnt   = (int*)alloc((size_t)nbk * 4);
    int*   bcur   = (int*)alloc((size_t)nbk * 4);
    float* gsum   = (float*)alloc((size_t)B * 128 * 4);
    float* cnt    = (float*)alloc((size_t)B * 4);
    size_t zbytes = (size_t)(p - (char*)d_ws);   // region zeroed each call
    int*   boff   = (int*)alloc((size_t)(nbk + 1) * 4);
    uint2* pairs  = (uint2*)alloc((size_t)E * 8);
    int*   off    = (int*)alloc((size_t)(N + 1) * 4);
    int*   col    = (int*)alloc((size_t)E * 4);
    float* dinv   = (float*)alloc((size_t)N * 4);
    __hip_bfloat16* Wc  = (__hip_bfloat16*)alloc((size_t)6 * 16384 * 2);  // bf16 weights: g1,g2,q,k,v,skip
    __hip_bfloat16* X0b = (__hip_bfloat16*)alloc((size_t)N * 128 * 2);    // x0 / x2
    __hip_bfloat16* X1b = (__hip_bfloat16*)alloc((size_t)N * 128 * 2);    // x1
    ushort_t* XW8 = (ushort_t*)alloc((size_t)N * 128);                    // fp8 xw' (prescaled, x32)
    uint*  KV8 = (uint*)alloc((size_t)N * 256);                           // fp8 head-blocked [k,k,v,v] dwords (x16)
    __hip_bfloat16* Cqb = (__hip_bfloat16*)alloc((size_t)N * 128 * 2);    // q bf16 (x 0.25/16)
    __hip_bfloat16* Bb  = (__hip_bfloat16*)alloc((size_t)N * 128 * 2);    // skip + attn out, bf16
    if ((size_t)(p - (char*)d_ws) > ws_size) return;

    (void)hipMemsetAsync(d_ws, 0, zbytes, stream);

    const __hip_bfloat16* Wg1b  = Wc + 0 * 16384;
    const __hip_bfloat16* Wg2b  = Wc + 1 * 16384;
    const __hip_bfloat16* Wqkvs = Wc + 2 * 16384;   // q,k,v,skip contiguous
    k_cvt6<<<384, 256, 0, stream>>>(W_g1, W_g2, Wq, Wk, Wv, Wskip, Wc);

    int gC = (E + CHUNK - 1) / CHUNK;
    k_bcount<<<gC, 1024, 0, stream>>>(ei, bcnt, E, nbk);
    k_bscan<<<1, 1024, 0, stream>>>(bcnt, boff, nbk);
    k_bfill<<<gC, 1024, 0, stream>>>(ei, boff, bcur, pairs, E, nbk);
    k_bucket<<<nbk, 256, 0, stream>>>(pairs, boff, off, dinv, col, N, nbk, E);

    int gN = (N + 3) / 4;       // gather kernels: 4 waves/block, 1 node/wave
    int gM = (N + 63) / 64;     // MFMA kernels: 64 rows/block

    k_linear<32, true, true, __hip_bfloat16><<<2048, 256, 0, stream>>>(nf, W_emb, b_emb, X0b, N);   // x0 bf16
    k_lin_mfma_scale<<<gM, 256, 0, stream>>>(X0b, Wg1b, dinv, XW8, N);                              // xw1' fp8
    k_gcn_agg<<<gN, 256, 0, stream>>>(XW8, off, col, dinv, b_g1, (__hip_bfloat162*)X1b, N);         // x1
    k_lin_mfma_scale<<<gM, 256, 0, stream>>>(X1b, Wg2b, dinv, XW8, N);                              // xw2' fp8
    k_gcn_agg<<<gN, 256, 0, stream>>>(XW8, off, col, dinv, b_g2, (__hip_bfloat162*)X0b, N);         // x2

    k_qkvs_mfma<<<gM, 256, 0, stream>>>(X0b, Wqkvs, bq, bk, bv, bskip, Cqb, KV8, Bb, N);            // q,KV,skip
    k_attn<<<gN, 256, 0, stream>>>((const uint*)Cqb, KV8, off, col, (uint*)Bb, N);                  // Bb += attn

    k_pool<<<gM, 128, 0, stream>>>(Bb, batch, gsum, cnt, N);

    float* out_qv = (float*)d_out;
    float* out_h  = out_qv + (size_t)B * 14;
    float* out_c  = out_h + (size_t)B * 128;
    k_final<<<B, 128, 0, stream>>>(gsum, cnt, w, Wgam, bgam, Wbet, bbet, hprev, cprev,
                                   Wih, bih, Whh, bhh, lng, lnb,
                                   Wa1, ba1, Wa2, ba2, Wv1, bv1, Wv2, bv2,
                                   out_qv, out_h, out_c);
}

// Round 17
// 325.143 us; speedup vs baseline: 1.1528x; 1.1383x over previous
//
#include <hip/hip_runtime.h>
#include <hip/hip_bf16.h>
#include <math.h>

typedef unsigned int uint;
typedef unsigned short ushort_t;
typedef __bf16 bf16_t;
typedef bf16_t bf16x8 __attribute__((ext_vector_type(8)));
typedef float f32x4 __attribute__((ext_vector_type(4)));
typedef float f32x2 __attribute__((ext_vector_type(2)));

__device__ inline float2 bf2_unpack(uint u) {
    union { uint i; float f; } a, b;
    a.i = u << 16;
    b.i = u & 0xffff0000u;
    return make_float2(a.f, b.f);   // (lo, hi)
}

__device__ inline uint bf2_pack(float lo, float hi) {
    __hip_bfloat162 h;
    h.x = __float2bfloat16(lo);
    h.y = __float2bfloat16(hi);
    return *(uint*)&h;              // hi<<16 | lo
}

// fp8 e4m3 (OCP) pack/unpack via HW converts (word selector must be compile-time const)
template<bool WORD>
__device__ __forceinline__ float2 fp8x2_unpack(uint u) {
    f32x2 r = __builtin_amdgcn_cvt_pk_f32_fp8((int)u, WORD);
    return make_float2(r[0], r[1]);
}
__device__ __forceinline__ int fp8x2_pack(float a, float b) {
    return __builtin_amdgcn_cvt_pk_fp8_f32(a, b, 0, false);  // bytes [a,b] in low 16
}

__device__ inline void store_out(float* p, float v) { *p = v; }
__device__ inline void store_out(__hip_bfloat16* p, float v) { *p = __float2bfloat16(v); }

#define RFL(x) __builtin_amdgcn_readfirstlane(x)

#define SCL_XW 32.f
#define SCL_KV 16.f
#define BK_SH 5               // 32 dst nodes per bucket
#define CHUNK 16384           // edges per binning block

// ---------------- bucketed CSR build: LDS-histogram binning (low-contention) ----------------
__global__ __launch_bounds__(1024) void k_bcount(const int* __restrict__ ei, int* __restrict__ bcnt,
                                                 int E, int nbk) {
    __shared__ int hist[2048];
    int t = threadIdx.x;
    for (int i = t; i < nbk; i += 1024) hist[i] = 0;
    __syncthreads();
    int e0 = blockIdx.x * CHUNK;
    int e1 = e0 + CHUNK; if (e1 > E) e1 = E;
    for (int e = e0 + t; e < e1; e += 1024)
        atomicAdd(&hist[(uint)ei[E + e] >> BK_SH], 1);
    __syncthreads();
    for (int i = t; i < nbk; i += 1024) {
        int c = hist[i];
        if (c) atomicAdd(&bcnt[i], c);
    }
}

// single-block chunked exclusive scan over nbk buckets; boff[nbk] = E
__global__ __launch_bounds__(1024) void k_bscan(const int* __restrict__ bcnt, int* __restrict__ boff, int nbk) {
    __shared__ int tmp[1024];
    int t = threadIdx.x;
    int per = (nbk + 1023) >> 10;
    int s0 = t * per, s1 = s0 + per; if (s1 > nbk) s1 = nbk;
    int sum = 0;
    for (int i = s0; i < s1; ++i) sum += bcnt[i];
    tmp[t] = sum;
    __syncthreads();
    for (int d = 1; d < 1024; d <<= 1) {
        int a = (t >= d) ? tmp[t - d] : 0;
        __syncthreads();
        tmp[t] += a;
        __syncthreads();
    }
    int carry = tmp[t] - sum;
    for (int i = s0; i < s1; ++i) { boff[i] = carry; carry += bcnt[i]; }
    if (t == 1023) boff[nbk] = tmp[1023];
}

// binned scatter: per-block LDS histogram -> one reservation atomic per (block,bucket) -> run writes
__global__ __launch_bounds__(1024) void k_bfill(const int* __restrict__ ei, const int* __restrict__ boff,
                                                int* __restrict__ bcur, uint2* __restrict__ pairs,
                                                int E, int nbk) {
    __shared__ int hist[2048];
    __shared__ int basep[2048];
    int t = threadIdx.x;
    for (int i = t; i < nbk; i += 1024) hist[i] = 0;
    __syncthreads();
    int e0 = blockIdx.x * CHUNK;
    int e1 = e0 + CHUNK; if (e1 > E) e1 = E;
    for (int e = e0 + t; e < e1; e += 1024)
        atomicAdd(&hist[(uint)ei[E + e] >> BK_SH], 1);
    __syncthreads();
    for (int i = t; i < nbk; i += 1024) {
        int c = hist[i];
        basep[i] = c ? atomicAdd(&bcur[i], c) : 0;
        hist[i] = 0;                                   // reuse as local cursor
    }
    __syncthreads();
    for (int e = e0 + t; e < e1; e += 1024) {
        int d = ei[E + e];
        int s = ei[e];
        int b = (uint)d >> BK_SH;
        int p = atomicAdd(&hist[b], 1);                // LDS cursor
        pairs[boff[b] + basep[b] + p] = make_uint2((uint)d, (uint)s);
    }
}

// one block per bucket: LDS per-dst count + scan -> off/dinv; then local scatter of col
__global__ __launch_bounds__(256) void k_bucket(const uint2* __restrict__ pairs, const int* __restrict__ boff,
                                                int* __restrict__ off, float* __restrict__ dinv,
                                                int* __restrict__ col, int N, int nbk, int E) {
    int b = blockIdx.x, t = threadIdx.x;
    __shared__ int cnt[32], excl[32], cur[32];
    int base = boff[b], end = boff[b + 1];
    if (t < 32) cnt[t] = 0;
    __syncthreads();
    for (int i = base + t; i < end; i += 256) {
        uint2 p = pairs[i];
        atomicAdd(&cnt[p.x & 31], 1);
    }
    __syncthreads();
    if (t == 0) {
        int run = base;
        #pragma unroll
        for (int j = 0; j < 32; ++j) { excl[j] = run; cur[j] = run; run += cnt[j]; }
    }
    __syncthreads();
    if (t < 32) {
        int node = (b << BK_SH) + t;
        if (node < N) {
            off[node] = excl[t];
            dinv[node] = rsqrtf((float)(cnt[t] + 1));   // self-loop adds 1
        }
    }
    if (b == nbk - 1 && t == 0) off[N] = E;
    for (int i = base + t; i < end; i += 256) {
        uint2 p = pairs[i];
        int pos = atomicAdd(&cur[p.x & 31], 1);
        col[pos] = (int)p.y;
    }
}

// ---------------- fp32 -> bf16 weight conversion (6 x 128x128 mats) ----------------
__global__ __launch_bounds__(256) void k_cvt6(const float* __restrict__ s0, const float* __restrict__ s1,
                                              const float* __restrict__ s2, const float* __restrict__ s3,
                                              const float* __restrict__ s4, const float* __restrict__ s5,
                                              __hip_bfloat16* __restrict__ dst) {
    int i = blockIdx.x * 256 + threadIdx.x;
    if (i >= 6 * 16384) return;
    int m = i >> 14;
    const float* s = (m == 0) ? s0 : (m == 1) ? s1 : (m == 2) ? s2 : (m == 3) ? s3 : (m == 4) ? s4 : s5;
    dst[i] = __float2bfloat16(s[i & 16383]);
}

// ---------------- scalar linear for FI=32 (embed), bf16 out ----------------
template<int FI, bool BIAS, bool RELU, typename OUT>
__global__ __launch_bounds__(256) void k_linear(const float* __restrict__ x, const float* __restrict__ W,
                                                const float* __restrict__ b, OUT* __restrict__ y, int n) {
    __shared__ float4 Wt4[(FI / 4) * 128];
    __shared__ float4 xl[2][FI / 4];
    int t = threadIdx.x & 127;
    int h = threadIdx.x >> 7;
    {
        const float4* Wrow = (const float4*)(W + (size_t)t * FI);
        #pragma unroll
        for (int k4 = h * (FI / 8); k4 < (h + 1) * (FI / 8); ++k4) Wt4[k4 * 128 + t] = Wrow[k4];
    }
    float bias = 0.f;
    if (BIAS) bias = b[t];
    __syncthreads();
    for (int n0 = blockIdx.x * 2; n0 < n; n0 += gridDim.x * 2) {
        int nn = n0 + h;
        if (nn < n && t < FI / 4) xl[h][t] = ((const float4*)(x + (size_t)nn * FI))[t];
        __syncthreads();
        if (nn < n) {
            float acc = bias;
            #pragma unroll
            for (int k4 = 0; k4 < FI / 4; ++k4) {
                float4 xv = xl[h][k4];
                float4 wv = Wt4[k4 * 128 + t];
                acc += xv.x * wv.x + xv.y * wv.y + xv.z * wv.z + xv.w * wv.w;
            }
            if (RELU) acc = fmaxf(acc, 0.f);
            store_out(&y[(size_t)nn * 128 + t], acc);
        }
        __syncthreads();
    }
}

// ---- shared helpers for LDS-staged W (32 KB mat, 16B-slot XOR swizzle) ----
__device__ __forceinline__ void stage_w(const bf16_t* __restrict__ Wm, uint* __restrict__ lw) {
    for (int c = threadIdx.x; c < 2048; c += 256) {          // 2048 x 16B chunks
        uint4 v = ((const uint4*)Wm)[c];
        int row = c >> 4, ch = c & 15;
        ((uint4*)lw)[(row << 4) + (ch ^ (row & 7))] = v;
    }
}
__device__ __forceinline__ bf16x8 lds_frag(const uint* __restrict__ lw, int wrow, int chunk) {
    int slot = (wrow << 4) + (chunk ^ (wrow & 7));
    return *(const bf16x8*)((const uint4*)lw + slot);
}

// ---------------- MFMA linear with per-row dinv prescale, fp8 x SCL_XW out, LDS-staged W --------
__global__ __launch_bounds__(256) void k_lin_mfma_scale(const __hip_bfloat16* __restrict__ X,
                                                        const __hip_bfloat16* __restrict__ W,
                                                        const float* __restrict__ dinv,
                                                        ushort_t* __restrict__ XW8, int n) {
    __shared__ __align__(16) uint lw[8192];
    int wave = threadIdx.x >> 6, lane = threadIdx.x & 63;
    stage_w((const bf16_t*)W, lw);
    int r0 = blockIdx.x * 64 + wave * 16;
    int mrow = r0 + (lane & 15);
    if (mrow >= n) mrow = n - 1;
    int kk4 = lane >> 4;
    const bf16x8* xr = (const bf16x8*)((const bf16_t*)X + (size_t)mrow * 128);
    bf16x8 a0 = xr[0 * 4 + kk4];
    bf16x8 a1 = xr[1 * 4 + kk4];
    bf16x8 a2 = xr[2 * 4 + kk4];
    bf16x8 a3 = xr[3 * 4 + kk4];
    int orow = (lane >> 4) * 4;
    int ocol = lane & 15;
    float dv[4];
    #pragma unroll
    for (int j = 0; j < 4; ++j) {
        int row = r0 + orow + j;
        dv[j] = ((row < n) ? dinv[row] : 0.f) * SCL_XW;
    }
    __syncthreads();
    #pragma unroll
    for (int c = 0; c < 8; ++c) {
        int wrow = c * 16 + (lane & 15);
        bf16x8 b0 = lds_frag(lw, wrow, 0 * 4 + kk4);
        bf16x8 b1 = lds_frag(lw, wrow, 1 * 4 + kk4);
        bf16x8 b2 = lds_frag(lw, wrow, 2 * 4 + kk4);
        bf16x8 b3 = lds_frag(lw, wrow, 3 * 4 + kk4);
        f32x4 acc = {0.f, 0.f, 0.f, 0.f};
        acc = __builtin_amdgcn_mfma_f32_16x16x32_bf16(a0, b0, acc, 0, 0, 0);
        acc = __builtin_amdgcn_mfma_f32_16x16x32_bf16(a1, b1, acc, 0, 0, 0);
        acc = __builtin_amdgcn_mfma_f32_16x16x32_bf16(a2, b2, acc, 0, 0, 0);
        acc = __builtin_amdgcn_mfma_f32_16x16x32_bf16(a3, b3, acc, 0, 0, 0);
        int gcol = c * 16 + ocol;
        #pragma unroll
        for (int j = 0; j < 4; ++j) {
            int row = r0 + orow + j;
            float v = acc[j] * dv[j];
            float vnb = __shfl_down(v, 1);
            if (((lane & 1) == 0) && row < n) {
                int pk = fp8x2_pack(v, vnb);
                XW8[(size_t)row * 64 + (gcol >> 1)] = (ushort_t)(pk & 0xffff);
            }
        }
    }
}

// ---------------- fused q/k/v/skip MFMA, LDS-staged W per mat ----------------
// KV8 dword (idx = gcol>>1 within row of 64): bytes [k(2d), k(2d+1), v(2d), v(2d+1)] fp8 x SCL_KV
__global__ __launch_bounds__(256) void k_qkvs_mfma(const __hip_bfloat16* __restrict__ X,
                                                   const __hip_bfloat16* __restrict__ W4,
                                                   const float* __restrict__ bq, const float* __restrict__ bk,
                                                   const float* __restrict__ bv, const float* __restrict__ bs,
                                                   __hip_bfloat16* __restrict__ Cqb, uint* __restrict__ KV8,
                                                   __hip_bfloat16* __restrict__ Bb, int n) {
    __shared__ __align__(16) uint lw[8192];
    int wave = threadIdx.x >> 6, lane = threadIdx.x & 63;
    int r0 = blockIdx.x * 64 + wave * 16;
    int mrow = r0 + (lane & 15);
    if (mrow >= n) mrow = n - 1;
    int kk4 = lane >> 4;
    const bf16x8* xr = (const bf16x8*)((const bf16_t*)X + (size_t)mrow * 128);
    bf16x8 a0 = xr[0 * 4 + kk4];
    bf16x8 a1 = xr[1 * 4 + kk4];
    bf16x8 a2 = xr[2 * 4 + kk4];
    bf16x8 a3 = xr[3 * 4 + kk4];
    int orow = (lane >> 4) * 4;
    int ocol = lane & 15;
    float karr[32];
    #pragma unroll
    for (int m = 0; m < 4; ++m) {
        __syncthreads();                                  // prior reads done before overwrite
        stage_w((const bf16_t*)W4 + (size_t)m * 16384, lw);
        __syncthreads();
        const float* bias = (m == 0) ? bq : (m == 1) ? bk : (m == 2) ? bv : bs;
        #pragma unroll
        for (int c = 0; c < 8; ++c) {
            int wrow = c * 16 + (lane & 15);
            bf16x8 b0 = lds_frag(lw, wrow, 0 * 4 + kk4);
            bf16x8 b1 = lds_frag(lw, wrow, 1 * 4 + kk4);
            bf16x8 b2 = lds_frag(lw, wrow, 2 * 4 + kk4);
            bf16x8 b3 = lds_frag(lw, wrow, 3 * 4 + kk4);
            f32x4 acc = {0.f, 0.f, 0.f, 0.f};
            acc = __builtin_amdgcn_mfma_f32_16x16x32_bf16(a0, b0, acc, 0, 0, 0);
            acc = __builtin_amdgcn_mfma_f32_16x16x32_bf16(a1, b1, acc, 0, 0, 0);
            acc = __builtin_amdgcn_mfma_f32_16x16x32_bf16(a2, b2, acc, 0, 0, 0);
            acc = __builtin_amdgcn_mfma_f32_16x16x32_bf16(a3, b3, acc, 0, 0, 0);
            int gcol = c * 16 + ocol;
            float bb = bias[gcol];
            #pragma unroll
            for (int j = 0; j < 4; ++j) {
                int row = r0 + orow + j;
                float v = acc[j] + bb;
                if (m == 1) karr[c * 4 + j] = v * SCL_KV;
                if (m == 0) {
                    if (row < n) store_out(&Cqb[(size_t)row * 128 + gcol], v * (0.25f / SCL_KV));
                } else if (m == 2) {
                    float vv = v * SCL_KV;
                    float kk = karr[c * 4 + j];
                    float kn = __shfl_down(kk, 1);
                    float vn = __shfl_down(vv, 1);
                    if (((lane & 1) == 0) && row < n) {
                        int pkk = fp8x2_pack(kk, kn);
                        int pkv = fp8x2_pack(vv, vn);
                        uint u = ((uint)pkk & 0xffffu) | ((uint)pkv << 16);
                        KV8[(size_t)row * 64 + (gcol >> 1)] = u;
                    }
                } else if (m == 3) {
                    if (row < n) store_out(&Bb[(size_t)row * 128 + gcol], v);
                }
            }
        }
    }
}

// ---------------- GCN aggregation: 1 wave/node, fp8 payload, 3-stage pipeline ----------------
__device__ __forceinline__ void gcn_cols(const int* __restrict__ col, int i, int (&c)[8]) {
    #pragma unroll
    for (int j = 0; j < 8; ++j) c[j] = RFL(col[i + j]);
}

__device__ __forceinline__ void gcn_issue(const ushort_t* __restrict__ xw, int lane,
                                          const int (&c)[8], uint (&u)[8]) {
    #pragma unroll
    for (int j = 0; j < 8; ++j) u[j] = (uint)xw[(size_t)c[j] * 64 + lane];
}

__device__ __forceinline__ void gcn_proc8(const uint (&u)[8], float2& acc) {
    float sx = 0.f, sy = 0.f;
    #pragma unroll
    for (int j = 0; j < 8; ++j) {
        float2 x = fp8x2_unpack<false>(u[j]);
        sx += x.x;
        sy += x.y;
    }
    acc.x += sx;
    acc.y += sy;
}

__global__ __launch_bounds__(256) void k_gcn_agg(const ushort_t* __restrict__ xw, const int* __restrict__ off,
                                                 const int* __restrict__ col, const float* __restrict__ dinv,
                                                 const float* __restrict__ bias, __hip_bfloat162* __restrict__ y, int n) {
    int wid = RFL((int)((blockIdx.x * 256 + threadIdx.x) >> 6));
    int lane = threadIdx.x & 63;
    if (wid >= n) return;
    float di = dinv[wid] * (1.f / SCL_XW);
    float2 acc = fp8x2_unpack<false>((uint)xw[(size_t)wid * 64 + lane]);
    int i = RFL(off[wid]), i1 = RFL(off[wid + 1]);
    int nfull = (i1 - i) >> 3;
    if (nfull > 0) {
        int cA[8], cB[8];
        uint ua[8], ub[8];
        gcn_cols(col, i, cA);            // cols chunk 0
        gcn_issue(xw, lane, cA, ua);     // data chunk 0
        if (nfull > 1) gcn_cols(col, i + 8, cB);
        int t = 0;
        while (true) {
            bool hasN = (t + 1 < nfull);
            if (hasN) gcn_issue(xw, lane, cB, ub);
            if (t + 2 < nfull) gcn_cols(col, i + 8 * (t + 2), cA);
            gcn_proc8(ua, acc);
            ++t; if (!hasN) break;
            hasN = (t + 1 < nfull);
            if (hasN) gcn_issue(xw, lane, cA, ua);
            if (t + 2 < nfull) gcn_cols(col, i + 8 * (t + 2), cB);
            gcn_proc8(ub, acc);
            ++t; if (!hasN) break;
        }
        i += nfull * 8;
    }
    for (; i < i1; ++i) {
        int c0 = RFL(col[i]);
        float2 x0 = fp8x2_unpack<false>((uint)xw[(size_t)c0 * 64 + lane]);
        acc.x += x0.x;
        acc.y += x0.y;
    }
    float2 b2 = ((const float2*)bias)[lane];
    __hip_bfloat162 o;
    o.x = __float2bfloat16(fmaxf(di * acc.x + b2.x, 0.f));
    o.y = __float2bfloat16(fmaxf(di * acc.y + b2.y, 0.f));
    y[(size_t)wid * 64 + lane] = o;
}

// ---------------- transformer attention: head-per-lane-group, 3-stage pipeline ----------------
// lane = (h = lane>>3, j = lane&7). Lane holds all 16 q feats of head h, processes edge i+j.
// KV row = 64 dwords; head h occupies dwords [h*8, h*8+8), dword d = [k2d,k2d+1,v2d,v2d+1] fp8.
__device__ __forceinline__ void attn_chunk(uint4 A, uint4 Bv, bool act, const float (&qf)[16],
                                           float& m, float& s, float (&acc)[16]) {
    uint au[8] = {A.x, A.y, A.z, A.w, Bv.x, Bv.y, Bv.z, Bv.w};
    float l = 0.f;
    #pragma unroll
    for (int d = 0; d < 8; ++d) {
        float2 kk = fp8x2_unpack<false>(au[d]);
        l = fmaf(qf[2 * d], kk.x, l);
        l = fmaf(qf[2 * d + 1], kk.y, l);
    }
    if (!act) l = -INFINITY;
    float mx = l;
    mx = fmaxf(mx, __shfl_xor(mx, 1));
    mx = fmaxf(mx, __shfl_xor(mx, 2));
    mx = fmaxf(mx, __shfl_xor(mx, 4));
    if (mx > m) {
        float corr = __expf(m - mx);     // 0 on first real chunk (m=-inf)
        s *= corr;
        #pragma unroll
        for (int f = 0; f < 16; ++f) acc[f] *= corr;
        m = mx;
    }
    float e = act ? __expf(l - m) : 0.f;
    s += e;
    #pragma unroll
    for (int d = 0; d < 8; ++d) {
        float2 vv = fp8x2_unpack<true>(au[d]);
        acc[2 * d] = fmaf(e, vv.x, acc[2 * d]);
        acc[2 * d + 1] = fmaf(e, vv.y, acc[2 * d + 1]);
    }
}

__global__ __launch_bounds__(256) void k_attn(const uint* __restrict__ qb, const uint* __restrict__ kv8,
                                              const int* __restrict__ off, const int* __restrict__ col,
                                              uint* __restrict__ io, int n) {
    int wid = RFL((int)((blockIdx.x * 256 + threadIdx.x) >> 6));
    int lane = threadIdx.x & 63;
    int h = lane >> 3, j = lane & 7;
    if (wid >= n) return;
    float qf[16];
    {
        const uint4* q4 = (const uint4*)(qb + (size_t)wid * 64 + h * 8);
        uint4 qa = q4[0], qc = q4[1];
        uint qu[8] = {qa.x, qa.y, qa.z, qa.w, qc.x, qc.y, qc.z, qc.w};
        #pragma unroll
        for (int d = 0; d < 8; ++d) {
            float2 t = bf2_unpack(qu[d]);
            qf[2 * d] = t.x;
            qf[2 * d + 1] = t.y;
        }
    }
    float acc[16];
    #pragma unroll
    for (int f = 0; f < 16; ++f) acc[f] = 0.f;
    float m = -INFINITY, s = 0.f;
    int i0 = RFL(off[wid]), i1 = RFL(off[wid + 1]);
    int nch = (i1 - i0 + 7) >> 3;   // masked 8-edge chunks
    if (nch > 0) {
        bool actA, actB = false, okA, okB = false;
        int colA, colB = 0;
        uint4 KA0, KA1, KB0, KB1;
        {
            int idx = i0 + j; actA = idx < i1;
            colA = col[actA ? idx : (i1 - 1)];
        }
        {
            const uint4* pb = (const uint4*)(kv8 + ((size_t)(uint)colA << 6) + (h << 3));
            KA0 = pb[0]; KA1 = pb[1]; okA = actA;
        }
        if (nch > 1) {
            int idx = i0 + 8 + j; actB = idx < i1;
            colB = col[actB ? idx : (i1 - 1)];
        }
        int t = 0;
        while (true) {
            bool hasN = (t + 1 < nch);
            if (hasN) {
                const uint4* pb = (const uint4*)(kv8 + ((size_t)(uint)colB << 6) + (h << 3));
                KB0 = pb[0]; KB1 = pb[1]; okB = actB;
            }
            if (t + 2 < nch) {
                int idx = i0 + 8 * (t + 2) + j; actA = idx < i1;
                colA = col[actA ? idx : (i1 - 1)];
            }
            attn_chunk(KA0, KA1, okA, qf, m, s, acc);
            ++t; if (!hasN) break;
            hasN = (t + 1 < nch);
            if (hasN) {
                const uint4* pb = (const uint4*)(kv8 + ((size_t)(uint)colA << 6) + (h << 3));
                KA0 = pb[0]; KA1 = pb[1]; okA = actA;
            }
            if (t + 2 < nch) {
                int idx = i0 + 8 * (t + 2) + j; actB = idx < i1;
                colB = col[actB ? idx : (i1 - 1)];
            }
            attn_chunk(KB0, KB1, okB, qf, m, s, acc);
            ++t; if (!hasN) break;
        }
    }
    // s total over the 8 edge-slot lanes of this head
    s += __shfl_xor(s, 1);
    s += __shfl_xor(s, 2);
    s += __shfl_xor(s, 4);
    // fold acc 16 -> 8 -> 4 -> 2; lane j ends with feats 2j, 2j+1 of head h
    float r8[8];
    #pragma unroll
    for (int f = 0; f < 8; ++f) {
        float send = (j & 4) ? acc[f] : acc[f + 8];
        float recv = __shfl_xor(send, 4);
        r8[f] = ((j & 4) ? acc[f + 8] : acc[f]) + recv;
    }
    float r4[4];
    #pragma unroll
    for (int f = 0; f < 4; ++f) {
        float send = (j & 2) ? r8[f] : r8[f + 4];
        float recv = __shfl_xor(send, 2);
        r4[f] = ((j & 2) ? r8[f + 4] : r8[f]) + recv;
    }
    float r2[2];
    #pragma unroll
    for (int f = 0; f < 2; ++f) {
        float send = (j & 1) ? r4[f] : r4[f + 2];
        float recv = __shfl_xor(send, 1);
        r2[f] = ((j & 1) ? r4[f + 2] : r4[f]) + recv;
    }
    float inv = (1.f / SCL_KV) / fmaxf(s, 1e-16f);
    uint* orow = io + (size_t)wid * 64 + lane;   // uint idx = h*8 + j
    float2 o2 = bf2_unpack(*orow);               // skip connection already there
    o2.x += r2[0] * inv;
    o2.y += r2[1] * inv;
    *orow = bf2_pack(o2.x, o2.y);
}

// ---------------- mean-pool per graph (batch sorted), bf16 in, 64 nodes/block ----------------
__global__ __launch_bounds__(128) void k_pool(const __hip_bfloat16* __restrict__ x, const int* __restrict__ batch,
                                              float* __restrict__ gsum, float* __restrict__ cnt, int n) {
    int t = threadIdx.x;
    int start = blockIdx.x * 64;
    int end = start + 64; if (end > n) end = n;
    if (start >= n) return;
    int cur = batch[start];
    float acc = 0.f;
    int run = 0;
    for (int nn = start; nn < end; ++nn) {
        int g = batch[nn];
        if (g != cur) {
            atomicAdd(&gsum[cur * 128 + t], acc);
            if (t == 0) atomicAdd(&cnt[cur], (float)run);
            acc = 0.f; run = 0; cur = g;
        }
        acc += __bfloat162float(x[(size_t)nn * 128 + t]);
        run++;
    }
    atomicAdd(&gsum[cur * 128 + t], acc);
    if (t == 0) atomicAdd(&cnt[cur], (float)run);
}

// ---------------- FiLM + LSTM + LayerNorm + dueling heads, one block per graph ----------------
__global__ __launch_bounds__(128) void k_final(
    const float* __restrict__ gsum, const float* __restrict__ cnt, const float* __restrict__ w,
    const float* __restrict__ Wgam, const float* __restrict__ bgam,
    const float* __restrict__ Wbet, const float* __restrict__ bbet,
    const float* __restrict__ hprev, const float* __restrict__ cprev,
    const float* __restrict__ Wih, const float* __restrict__ bih,
    const float* __restrict__ Whh, const float* __restrict__ bhh,
    const float* __restrict__ lng, const float* __restrict__ lnb,
    const float* __restrict__ Wa1, const float* __restrict__ ba1,
    const float* __restrict__ Wa2, const float* __restrict__ ba2,
    const float* __restrict__ Wv1, const float* __restrict__ bv1,
    const float* __restrict__ Wv2, const float* __restrict__ bv2,
    float* __restrict__ out_qv, float* __restrict__ out_h, float* __restrict__ out_c) {
    int g = blockIdx.x, t = threadIdx.x;
    __shared__ __align__(16) float ge[128], hp[128], hn[128], r1[128], a1s[128], red[128];
    __shared__ float adv[16], val[2], mu_s, var_s;

    float w0 = w[g * 2 + 0], w1 = w[g * 2 + 1];
    float c = fmaxf(cnt[g], 1.f);
    float mn = gsum[g * 128 + t] / c;
    float gam = w0 * Wgam[2 * t] + w1 * Wgam[2 * t + 1] + bgam[t];
    float bet = w0 * Wbet[2 * t] + w1 * Wbet[2 * t + 1] + bbet[t];
    ge[t] = (1.f + gam) * mn + bet;
    hp[t] = hprev[g * 128 + t];
    __syncthreads();

    float gi = bih[t] + bhh[t];
    float gf = bih[128 + t] + bhh[128 + t];
    float gg = bih[256 + t] + bhh[256 + t];
    float go = bih[384 + t] + bhh[384 + t];
    {
        const float4* ge4 = (const float4*)ge;
        const float4* hp4 = (const float4*)hp;
        const float4* Ai = (const float4*)(Wih + (size_t)t * 128);
        const float4* Af = (const float4*)(Wih + (size_t)(128 + t) * 128);
        const float4* Ag = (const float4*)(Wih + (size_t)(256 + t) * 128);
        const float4* Ao = (const float4*)(Wih + (size_t)(384 + t) * 128);
        const float4* Hi = (const float4*)(Whh + (size_t)t * 128);
        const float4* Hf = (const float4*)(Whh + (size_t)(128 + t) * 128);
        const float4* Hg = (const float4*)(Whh + (size_t)(256 + t) * 128);
        const float4* Ho = (const float4*)(Whh + (size_t)(384 + t) * 128);
        #pragma unroll 4
        for (int k4 = 0; k4 < 32; ++k4) {
            float4 a = ge4[k4], h4 = hp4[k4], u;
            u = Ai[k4]; gi += a.x * u.x + a.y * u.y + a.z * u.z + a.w * u.w;
            u = Hi[k4]; gi += h4.x * u.x + h4.y * u.y + h4.z * u.z + h4.w * u.w;
            u = Af[k4]; gf += a.x * u.x + a.y * u.y + a.z * u.z + a.w * u.w;
            u = Hf[k4]; gf += h4.x * u.x + h4.y * u.y + h4.z * u.z + h4.w * u.w;
            u = Ag[k4]; gg += a.x * u.x + a.y * u.y + a.z * u.z + a.w * u.w;
            u = Hg[k4]; gg += h4.x * u.x + h4.y * u.y + h4.z * u.z + h4.w * u.w;
            u = Ao[k4]; go += a.x * u.x + a.y * u.y + a.z * u.z + a.w * u.w;
            u = Ho[k4]; go += h4.x * u.x + h4.y * u.y + h4.z * u.z + h4.w * u.w;
        }
    }
    float ig = 1.f / (1.f + __expf(-gi));
    float fg = 1.f / (1.f + __expf(-gf));
    float gc = tanhf(gg);
    float og = 1.f / (1.f + __expf(-go));
    float craw = fg * cprev[g * 128 + t] + ig * gc;
    float hraw = og * tanhf(craw);
    out_c[g * 128 + t] = fminf(fmaxf(craw, -1e6f), 1e6f);

    red[t] = hraw;
    __syncthreads();
    for (int s2 = 64; s2 > 0; s2 >>= 1) { if (t < s2) red[t] += red[t + s2]; __syncthreads(); }
    if (t == 0) mu_s = red[0] * (1.f / 128.f);
    __syncthreads();
    float mu = mu_s;
    float d = hraw - mu;
    red[t] = d * d;
    __syncthreads();
    for (int s2 = 64; s2 > 0; s2 >>= 1) { if (t < s2) red[t] += red[t + s2]; __syncthreads(); }
    if (t == 0) var_s = red[0] * (1.f / 128.f);
    __syncthreads();
    float hv = d * rsqrtf(var_s + 1e-5f) * lng[t] + lnb[t];
    hn[t] = hv;
    out_h[g * 128 + t] = hv;
    __syncthreads();

    float accv = bv1[t], acca = ba1[t];
    {
        const float4* hn4 = (const float4*)hn;
        const float4* V1 = (const float4*)(Wv1 + (size_t)t * 128);
        const float4* A1 = (const float4*)(Wa1 + (size_t)t * 128);
        #pragma unroll 4
        for (int k4 = 0; k4 < 32; ++k4) {
            float4 hh = hn4[k4], u;
            u = V1[k4]; accv += hh.x * u.x + hh.y * u.y + hh.z * u.z + hh.w * u.w;
            u = A1[k4]; acca += hh.x * u.x + hh.y * u.y + hh.z * u.z + hh.w * u.w;
        }
    }
    r1[t] = fmaxf(accv, 0.f);
    a1s[t] = fmaxf(acca, 0.f);
    __syncthreads();
    if (t < 2) {
        float s = bv2[t];
        const float4* V2 = (const float4*)(Wv2 + (size_t)t * 128);
        const float4* r4 = (const float4*)r1;
        for (int k4 = 0; k4 < 32; ++k4) { float4 u = V2[k4], rr = r4[k4]; s += rr.x * u.x + rr.y * u.y + rr.z * u.z + rr.w * u.w; }
        val[t] = s;
    }
    if (t < 14) {
        float s = ba2[t];
        const float4* A2 = (const float4*)(Wa2 + (size_t)t * 128);
        const float4* a4 = (const float4*)a1s;
        for (int k4 = 0; k4 < 32; ++k4) { float4 u = A2[k4], aa = a4[k4]; s += aa.x * u.x + aa.y * u.y + aa.z * u.z + aa.w * u.w; }
        adv[t] = s;
    }
    __syncthreads();
    if (t < 14) {
        int o = t & 1;
        float mo = (adv[o] + adv[o + 2] + adv[o + 4] + adv[o + 6] + adv[o + 8] + adv[o + 10] + adv[o + 12]) * (1.f / 7.f);
        float qq = val[o] + adv[t] - mo;
        if (isnan(qq)) qq = 0.f;
        qq = fminf(fmaxf(qq, -100.f), 100.f);
        out_qv[g * 14 + t] = qq;
    }
}

extern "C" void kernel_launch(void* const* d_in, const int* in_sizes, int n_in,
                              void* d_out, int out_size, void* d_ws, size_t ws_size,
                              hipStream_t stream) {
    const float* nf    = (const float*)d_in[0];
    const int*   ei    = (const int*)d_in[1];
    const int*   batch = (const int*)d_in[2];
    const float* w     = (const float*)d_in[3];
    const float* hprev = (const float*)d_in[4];
    const float* cprev = (const float*)d_in[5];
    const float* W_emb = (const float*)d_in[6];  const float* b_emb = (const float*)d_in[7];
    const float* W_g1  = (const float*)d_in[8];  const float* b_g1  = (const float*)d_in[9];
    const float* W_g2  = (const float*)d_in[10]; const float* b_g2  = (const float*)d_in[11];
    const float* Wq    = (const float*)d_in[12]; const float* bq    = (const float*)d_in[13];
    const float* Wk    = (const float*)d_in[14]; const float* bk    = (const float*)d_in[15];
    const float* Wv    = (const float*)d_in[16]; const float* bv    = (const float*)d_in[17];
    const float* Wskip = (const float*)d_in[18]; const float* bskip = (const float*)d_in[19];
    const float* Wgam  = (const float*)d_in[20]; const float* bgam  = (const float*)d_in[21];
    const float* Wbet  = (const float*)d_in[22]; const float* bbet  = (const float*)d_in[23];
    const float* Wih   = (const float*)d_in[24]; const float* bih   = (const float*)d_in[25];
    const float* Whh   = (const float*)d_in[26]; const float* bhh   = (const float*)d_in[27];
    const float* lng   = (const float*)d_in[28]; const float* lnb   = (const float*)d_in[29];
    const float* Wa1   = (const float*)d_in[30]; const float* ba1   = (const float*)d_in[31];
    const float* Wa2   = (const float*)d_in[32]; const float* ba2   = (const float*)d_in[33];
    const float* Wv1   = (const float*)d_in[34]; const float* bv1   = (const float*)d_in[35];
    const float* Wv2   = (const float*)d_in[36]; const float* bv2   = (const float*)d_in[37];

    int N = in_sizes[2];
    int E = in_sizes[1] / 2;
    int B = in_sizes[4] / 128;
    int nbk = (N + 31) >> BK_SH;   // buckets of 32 dst nodes (<= 2048)

    char* p = (char*)d_ws;
    auto alloc = [&](size_t bytes) { char* r = p; p += (bytes + 511) & ~(size_t)511; return r; };
    int*   bcnt   = (int*)alloc((size_t)nbk * 4);
    int*   bcur   = (int*)alloc((size_t)nbk * 4);
    float* gsum   = (float*)alloc((size_t)B * 128 * 4);
    float* cnt    = (float*)alloc((size_t)B * 4);
    size_t zbytes = (size_t)(p - (char*)d_ws);   // region zeroed each call
    int*   boff   = (int*)alloc((size_t)(nbk + 1) * 4);
    uint2* pairs  = (uint2*)alloc((size_t)E * 8);
    int*   off    = (int*)alloc((size_t)(N + 1) * 4);
    int*   col    = (int*)alloc((size_t)E * 4);
    float* dinv   = (float*)alloc((size_t)N * 4);
    __hip_bfloat16* Wc  = (__hip_bfloat16*)alloc((size_t)6 * 16384 * 2);  // bf16 weights: g1,g2,q,k,v,skip
    __hip_bfloat16* X0b = (__hip_bfloat16*)alloc((size_t)N * 128 * 2);    // x0 / x2
    __hip_bfloat16* X1b = (__hip_bfloat16*)alloc((size_t)N * 128 * 2);    // x1
    ushort_t* XW8 = (ushort_t*)alloc((size_t)N * 128);                    // fp8 xw' (prescaled, x32)
    uint*  KV8 = (uint*)alloc((size_t)N * 256);                           // fp8 head-blocked [k,k,v,v] dwords (x16)
    __hip_bfloat16* Cqb = (__hip_bfloat16*)alloc((size_t)N * 128 * 2);    // q bf16 (x 0.25/16)
    __hip_bfloat16* Bb  = (__hip_bfloat16*)alloc((size_t)N * 128 * 2);    // skip + attn out, bf16
    if ((size_t)(p - (char*)d_ws) > ws_size) return;

    (void)hipMemsetAsync(d_ws, 0, zbytes, stream);

    const __hip_bfloat16* Wg1b  = Wc + 0 * 16384;
    const __hip_bfloat16* Wg2b  = Wc + 1 * 16384;
    const __hip_bfloat16* Wqkvs = Wc + 2 * 16384;   // q,k,v,skip contiguous
    k_cvt6<<<384, 256, 0, stream>>>(W_g1, W_g2, Wq, Wk, Wv, Wskip, Wc);

    int gC = (E + CHUNK - 1) / CHUNK;
    k_bcount<<<gC, 1024, 0, stream>>>(ei, bcnt, E, nbk);
    k_bscan<<<1, 1024, 0, stream>>>(bcnt, boff, nbk);
    k_bfill<<<gC, 1024, 0, stream>>>(ei, boff, bcur, pairs, E, nbk);
    k_bucket<<<nbk, 256, 0, stream>>>(pairs, boff, off, dinv, col, N, nbk, E);

    int gN = (N + 3) / 4;       // gather kernels: 4 waves/block, 1 node/wave
    int gM = (N + 63) / 64;     // MFMA kernels: 64 rows/block

    k_linear<32, true, true, __hip_bfloat16><<<2048, 256, 0, stream>>>(nf, W_emb, b_emb, X0b, N);   // x0 bf16
    k_lin_mfma_scale<<<gM, 256, 0, stream>>>(X0b, Wg1b, dinv, XW8, N);                              // xw1' fp8
    k_gcn_agg<<<gN, 256, 0, stream>>>(XW8, off, col, dinv, b_g1, (__hip_bfloat162*)X1b, N);         // x1
    k_lin_mfma_scale<<<gM, 256, 0, stream>>>(X1b, Wg2b, dinv, XW8, N);                              // xw2' fp8
    k_gcn_agg<<<gN, 256, 0, stream>>>(XW8, off, col, dinv, b_g2, (__hip_bfloat162*)X0b, N);         // x2

    k_qkvs_mfma<<<gM, 256, 0, stream>>>(X0b, Wqkvs, bq, bk, bv, bskip, Cqb, KV8, Bb, N);            // q,KV,skip
    k_attn<<<gN, 256, 0, stream>>>((const uint*)Cqb, KV8, off, col, (uint*)Bb, N);                  // Bb += attn

    k_pool<<<gM, 128, 0, stream>>>(Bb, batch, gsum, cnt, N);

    float* out_qv = (float*)d_out;
    float* out_h  = out_qv + (size_t)B * 14;
    float* out_c  = out_h + (size_t)B * 128;
    k_final<<<B, 128, 0, stream>>>(gsum, cnt, w, Wgam, bgam, Wbet, bbet, hprev, cprev,
                                   Wih, bih, Whh, bhh, lng, lnb,
                                   Wa1, ba1, Wa2, ba2, Wv1, bv1, Wv2, bv2,
                                   out_qv, out_h, out_c);
}

// Round 18
// 323.198 us; speedup vs baseline: 1.1598x; 1.0060x over previous
//
#include <hip/hip_runtime.h>
#include <hip/hip_bf16.h>
#include <math.h>

typedef unsigned int uint;
typedef unsigned short ushort_t;
typedef __bf16 bf16_t;
typedef bf16_t bf16x8 __attribute__((ext_vector_type(8)));
typedef float f32x4 __attribute__((ext_vector_type(4)));
typedef float f32x2 __attribute__((ext_vector_type(2)));

__device__ inline float2 bf2_unpack(uint u) {
    union { uint i; float f; } a, b;
    a.i = u << 16;
    b.i = u & 0xffff0000u;
    return make_float2(a.f, b.f);   // (lo, hi)
}

__device__ inline uint bf2_pack(float lo, float hi) {
    __hip_bfloat162 h;
    h.x = __float2bfloat16(lo);
    h.y = __float2bfloat16(hi);
    return *(uint*)&h;              // hi<<16 | lo
}

// fp8 e4m3 (OCP) pack/unpack via HW converts (word selector must be compile-time const)
template<bool WORD>
__device__ __forceinline__ float2 fp8x2_unpack(uint u) {
    f32x2 r = __builtin_amdgcn_cvt_pk_f32_fp8((int)u, WORD);
    return make_float2(r[0], r[1]);
}
__device__ __forceinline__ int fp8x2_pack(float a, float b) {
    return __builtin_amdgcn_cvt_pk_fp8_f32(a, b, 0, false);  // bytes [a,b] in low 16
}

__device__ inline void store_out(float* p, float v) { *p = v; }
__device__ inline void store_out(__hip_bfloat16* p, float v) { *p = __float2bfloat16(v); }

#define RFL(x) __builtin_amdgcn_readfirstlane(x)

#define SCL_XW 32.f
#define SCL_KV 16.f
#define BK_SH 5               // 32 dst nodes per bucket
#define CHUNK 8192            // edges per binning block

// ---------------- bucketed CSR build: LDS-histogram binning (low-contention) ----------------
__global__ __launch_bounds__(1024) void k_bcount(const int* __restrict__ ei, int* __restrict__ bcnt,
                                                 int E, int nbk) {
    __shared__ int hist[2048];
    int t = threadIdx.x;
    for (int i = t; i < nbk; i += 1024) hist[i] = 0;
    __syncthreads();
    int e0 = blockIdx.x * CHUNK;
    int e1 = e0 + CHUNK; if (e1 > E) e1 = E;
    for (int e = e0 + t; e < e1; e += 1024)
        atomicAdd(&hist[(uint)ei[E + e] >> BK_SH], 1);
    __syncthreads();
    for (int i = t; i < nbk; i += 1024) {
        int c = hist[i];
        if (c) atomicAdd(&bcnt[i], c);
    }
}

// single-block chunked exclusive scan over nbk buckets; boff[nbk] = E
__global__ __launch_bounds__(1024) void k_bscan(const int* __restrict__ bcnt, int* __restrict__ boff, int nbk) {
    __shared__ int tmp[1024];
    int t = threadIdx.x;
    int per = (nbk + 1023) >> 10;
    int s0 = t * per, s1 = s0 + per; if (s1 > nbk) s1 = nbk;
    int sum = 0;
    for (int i = s0; i < s1; ++i) sum += bcnt[i];
    tmp[t] = sum;
    __syncthreads();
    for (int d = 1; d < 1024; d <<= 1) {
        int a = (t >= d) ? tmp[t - d] : 0;
        __syncthreads();
        tmp[t] += a;
        __syncthreads();
    }
    int carry = tmp[t] - sum;
    for (int i = s0; i < s1; ++i) { boff[i] = carry; carry += bcnt[i]; }
    if (t == 1023) boff[nbk] = tmp[1023];
}

// binned scatter: per-block LDS histogram -> one reservation atomic per (block,bucket) -> run writes
__global__ __launch_bounds__(1024) void k_bfill(const int* __restrict__ ei, const int* __restrict__ boff,
                                                int* __restrict__ bcur, uint2* __restrict__ pairs,
                                                int E, int nbk) {
    __shared__ int hist[2048];
    __shared__ int basep[2048];
    int t = threadIdx.x;
    for (int i = t; i < nbk; i += 1024) hist[i] = 0;
    __syncthreads();
    int e0 = blockIdx.x * CHUNK;
    int e1 = e0 + CHUNK; if (e1 > E) e1 = E;
    for (int e = e0 + t; e < e1; e += 1024)
        atomicAdd(&hist[(uint)ei[E + e] >> BK_SH], 1);
    __syncthreads();
    for (int i = t; i < nbk; i += 1024) {
        int c = hist[i];
        basep[i] = c ? atomicAdd(&bcur[i], c) : 0;
        hist[i] = 0;                                   // reuse as local cursor
    }
    __syncthreads();
    for (int e = e0 + t; e < e1; e += 1024) {
        int d = ei[E + e];
        int s = ei[e];
        int b = (uint)d >> BK_SH;
        int p = atomicAdd(&hist[b], 1);                // LDS cursor
        pairs[boff[b] + basep[b] + p] = make_uint2((uint)d, (uint)s);
    }
}

// one block per bucket: LDS per-dst count + scan -> off/dinv; then local scatter of col
__global__ __launch_bounds__(256) void k_bucket(const uint2* __restrict__ pairs, const int* __restrict__ boff,
                                                int* __restrict__ off, float* __restrict__ dinv,
                                                int* __restrict__ col, int N, int nbk, int E) {
    int b = blockIdx.x, t = threadIdx.x;
    __shared__ int cnt[32], excl[32], cur[32];
    int base = boff[b], end = boff[b + 1];
    if (t < 32) cnt[t] = 0;
    __syncthreads();
    for (int i = base + t; i < end; i += 256) {
        uint2 p = pairs[i];
        atomicAdd(&cnt[p.x & 31], 1);
    }
    __syncthreads();
    if (t == 0) {
        int run = base;
        #pragma unroll
        for (int j = 0; j < 32; ++j) { excl[j] = run; cur[j] = run; run += cnt[j]; }
    }
    __syncthreads();
    if (t < 32) {
        int node = (b << BK_SH) + t;
        if (node < N) {
            off[node] = excl[t];
            dinv[node] = rsqrtf((float)(cnt[t] + 1));   // self-loop adds 1
        }
    }
    if (b == nbk - 1 && t == 0) off[N] = E;
    for (int i = base + t; i < end; i += 256) {
        uint2 p = pairs[i];
        int pos = atomicAdd(&cur[p.x & 31], 1);
        col[pos] = (int)p.y;
    }
}

// ---------------- fp32 -> bf16 weight conversion (6 x 128x128 mats) ----------------
__global__ __launch_bounds__(256) void k_cvt6(const float* __restrict__ s0, const float* __restrict__ s1,
                                              const float* __restrict__ s2, const float* __restrict__ s3,
                                              const float* __restrict__ s4, const float* __restrict__ s5,
                                              __hip_bfloat16* __restrict__ dst) {
    int i = blockIdx.x * 256 + threadIdx.x;
    if (i >= 6 * 16384) return;
    int m = i >> 14;
    const float* s = (m == 0) ? s0 : (m == 1) ? s1 : (m == 2) ? s2 : (m == 3) ? s3 : (m == 4) ? s4 : s5;
    dst[i] = __float2bfloat16(s[i & 16383]);
}

// ---------------- scalar linear for FI=32 (embed), bf16 out ----------------
template<int FI, bool BIAS, bool RELU, typename OUT>
__global__ __launch_bounds__(256) void k_linear(const float* __restrict__ x, const float* __restrict__ W,
                                                const float* __restrict__ b, OUT* __restrict__ y, int n) {
    __shared__ float4 Wt4[(FI / 4) * 128];
    __shared__ float4 xl[2][FI / 4];
    int t = threadIdx.x & 127;
    int h = threadIdx.x >> 7;
    {
        const float4* Wrow = (const float4*)(W + (size_t)t * FI);
        #pragma unroll
        for (int k4 = h * (FI / 8); k4 < (h + 1) * (FI / 8); ++k4) Wt4[k4 * 128 + t] = Wrow[k4];
    }
    float bias = 0.f;
    if (BIAS) bias = b[t];
    __syncthreads();
    for (int n0 = blockIdx.x * 2; n0 < n; n0 += gridDim.x * 2) {
        int nn = n0 + h;
        if (nn < n && t < FI / 4) xl[h][t] = ((const float4*)(x + (size_t)nn * FI))[t];
        __syncthreads();
        if (nn < n) {
            float acc = bias;
            #pragma unroll
            for (int k4 = 0; k4 < FI / 4; ++k4) {
                float4 xv = xl[h][k4];
                float4 wv = Wt4[k4 * 128 + t];
                acc += xv.x * wv.x + xv.y * wv.y + xv.z * wv.z + xv.w * wv.w;
            }
            if (RELU) acc = fmaxf(acc, 0.f);
            store_out(&y[(size_t)nn * 128 + t], acc);
        }
        __syncthreads();
    }
}

// ---- shared helpers for LDS-staged W (32 KB mat, 16B-slot XOR swizzle) ----
__device__ __forceinline__ void stage_w(const bf16_t* __restrict__ Wm, uint* __restrict__ lw) {
    for (int c = threadIdx.x; c < 2048; c += 256) {          // 2048 x 16B chunks
        uint4 v = ((const uint4*)Wm)[c];
        int row = c >> 4, ch = c & 15;
        ((uint4*)lw)[(row << 4) + (ch ^ (row & 7))] = v;
    }
}
__device__ __forceinline__ bf16x8 lds_frag(const uint* __restrict__ lw, int wrow, int chunk) {
    int slot = (wrow << 4) + (chunk ^ (wrow & 7));
    return *(const bf16x8*)((const uint4*)lw + slot);
}

// ---------------- MFMA linear with per-row dinv prescale, fp8 x SCL_XW out, LDS-staged W --------
__global__ __launch_bounds__(256) void k_lin_mfma_scale(const __hip_bfloat16* __restrict__ X,
                                                        const __hip_bfloat16* __restrict__ W,
                                                        const float* __restrict__ dinv,
                                                        ushort_t* __restrict__ XW8, int n) {
    __shared__ __align__(16) uint lw[8192];
    int wave = threadIdx.x >> 6, lane = threadIdx.x & 63;
    stage_w((const bf16_t*)W, lw);
    int r0 = blockIdx.x * 64 + wave * 16;
    int mrow = r0 + (lane & 15);
    if (mrow >= n) mrow = n - 1;
    int kk4 = lane >> 4;
    const bf16x8* xr = (const bf16x8*)((const bf16_t*)X + (size_t)mrow * 128);
    bf16x8 a0 = xr[0 * 4 + kk4];
    bf16x8 a1 = xr[1 * 4 + kk4];
    bf16x8 a2 = xr[2 * 4 + kk4];
    bf16x8 a3 = xr[3 * 4 + kk4];
    int orow = (lane >> 4) * 4;
    int ocol = lane & 15;
    float dv[4];
    #pragma unroll
    for (int j = 0; j < 4; ++j) {
        int row = r0 + orow + j;
        dv[j] = ((row < n) ? dinv[row] : 0.f) * SCL_XW;
    }
    __syncthreads();
    #pragma unroll
    for (int c = 0; c < 8; ++c) {
        int wrow = c * 16 + (lane & 15);
        bf16x8 b0 = lds_frag(lw, wrow, 0 * 4 + kk4);
        bf16x8 b1 = lds_frag(lw, wrow, 1 * 4 + kk4);
        bf16x8 b2 = lds_frag(lw, wrow, 2 * 4 + kk4);
        bf16x8 b3 = lds_frag(lw, wrow, 3 * 4 + kk4);
        f32x4 acc = {0.f, 0.f, 0.f, 0.f};
        acc = __builtin_amdgcn_mfma_f32_16x16x32_bf16(a0, b0, acc, 0, 0, 0);
        acc = __builtin_amdgcn_mfma_f32_16x16x32_bf16(a1, b1, acc, 0, 0, 0);
        acc = __builtin_amdgcn_mfma_f32_16x16x32_bf16(a2, b2, acc, 0, 0, 0);
        acc = __builtin_amdgcn_mfma_f32_16x16x32_bf16(a3, b3, acc, 0, 0, 0);
        int gcol = c * 16 + ocol;
        #pragma unroll
        for (int j = 0; j < 4; ++j) {
            int row = r0 + orow + j;
            float v = acc[j] * dv[j];
            float vnb = __shfl_down(v, 1);
            if (((lane & 1) == 0) && row < n) {
                int pk = fp8x2_pack(v, vnb);
                XW8[(size_t)row * 64 + (gcol >> 1)] = (ushort_t)(pk & 0xffff);
            }
        }
    }
}

// ---------------- fused q/k/v/skip MFMA, LDS-staged W per mat ----------------
// KV8 dword (idx = gcol>>1 within row of 64): bytes [k(2d), k(2d+1), v(2d), v(2d+1)] fp8 x SCL_KV
__global__ __launch_bounds__(256) void k_qkvs_mfma(const __hip_bfloat16* __restrict__ X,
                                                   const __hip_bfloat16* __restrict__ W4,
                                                   const float* __restrict__ bq, const float* __restrict__ bk,
                                                   const float* __restrict__ bv, const float* __restrict__ bs,
                                                   __hip_bfloat16* __restrict__ Cqb, uint* __restrict__ KV8,
                                                   __hip_bfloat16* __restrict__ Bb, int n) {
    __shared__ __align__(16) uint lw[8192];
    int wave = threadIdx.x >> 6, lane = threadIdx.x & 63;
    int r0 = blockIdx.x * 64 + wave * 16;
    int mrow = r0 + (lane & 15);
    if (mrow >= n) mrow = n - 1;
    int kk4 = lane >> 4;
    const bf16x8* xr = (const bf16x8*)((const bf16_t*)X + (size_t)mrow * 128);
    bf16x8 a0 = xr[0 * 4 + kk4];
    bf16x8 a1 = xr[1 * 4 + kk4];
    bf16x8 a2 = xr[2 * 4 + kk4];
    bf16x8 a3 = xr[3 * 4 + kk4];
    int orow = (lane >> 4) * 4;
    int ocol = lane & 15;
    float karr[32];
    #pragma unroll
    for (int m = 0; m < 4; ++m) {
        __syncthreads();                                  // prior reads done before overwrite
        stage_w((const bf16_t*)W4 + (size_t)m * 16384, lw);
        __syncthreads();
        const float* bias = (m == 0) ? bq : (m == 1) ? bk : (m == 2) ? bv : bs;
        #pragma unroll
        for (int c = 0; c < 8; ++c) {
            int wrow = c * 16 + (lane & 15);
            bf16x8 b0 = lds_frag(lw, wrow, 0 * 4 + kk4);
            bf16x8 b1 = lds_frag(lw, wrow, 1 * 4 + kk4);
            bf16x8 b2 = lds_frag(lw, wrow, 2 * 4 + kk4);
            bf16x8 b3 = lds_frag(lw, wrow, 3 * 4 + kk4);
            f32x4 acc = {0.f, 0.f, 0.f, 0.f};
            acc = __builtin_amdgcn_mfma_f32_16x16x32_bf16(a0, b0, acc, 0, 0, 0);
            acc = __builtin_amdgcn_mfma_f32_16x16x32_bf16(a1, b1, acc, 0, 0, 0);
            acc = __builtin_amdgcn_mfma_f32_16x16x32_bf16(a2, b2, acc, 0, 0, 0);
            acc = __builtin_amdgcn_mfma_f32_16x16x32_bf16(a3, b3, acc, 0, 0, 0);
            int gcol = c * 16 + ocol;
            float bb = bias[gcol];
            #pragma unroll
            for (int j = 0; j < 4; ++j) {
                int row = r0 + orow + j;
                float v = acc[j] + bb;
                if (m == 1) karr[c * 4 + j] = v * SCL_KV;
                if (m == 0) {
                    if (row < n) store_out(&Cqb[(size_t)row * 128 + gcol], v * (0.25f / SCL_KV));
                } else if (m == 2) {
                    float vv = v * SCL_KV;
                    float kk = karr[c * 4 + j];
                    float kn = __shfl_down(kk, 1);
                    float vn = __shfl_down(vv, 1);
                    if (((lane & 1) == 0) && row < n) {
                        int pkk = fp8x2_pack(kk, kn);
                        int pkv = fp8x2_pack(vv, vn);
                        uint u = ((uint)pkk & 0xffffu) | ((uint)pkv << 16);
                        KV8[(size_t)row * 64 + (gcol >> 1)] = u;
                    }
                } else if (m == 3) {
                    if (row < n) store_out(&Bb[(size_t)row * 128 + gcol], v);
                }
            }
        }
    }
}

// ---------------- GCN aggregation: dual-edge dword layout, 3-stage pipeline ----------------
// lane = (e = lane>>5, d = lane&31). Lane loads dword d (feats 4d..4d+3) of edge i+e.
// One wave-load covers 2 edges x 128 B. Halves fold via shfl_xor(32) at the end.
__device__ __forceinline__ void gcn2_proc(uint u, float& a0, float& a1, float& a2, float& a3) {
    float2 p = fp8x2_unpack<false>(u);
    float2 r = fp8x2_unpack<true>(u);
    a0 += p.x; a1 += p.y; a2 += r.x; a3 += r.y;
}

__global__ __launch_bounds__(256) void k_gcn_agg(const uint* __restrict__ xw32, const int* __restrict__ off,
                                                 const int* __restrict__ col, const float* __restrict__ dinv,
                                                 const float* __restrict__ bias, uint2* __restrict__ y, int n) {
    int wid = RFL((int)((blockIdx.x * 256 + threadIdx.x) >> 6));
    int lane = threadIdx.x & 63;
    int e = lane >> 5, d = lane & 31;
    if (wid >= n) return;
    float di = dinv[wid] * (1.f / SCL_XW);
    float a0 = 0.f, a1 = 0.f, a2 = 0.f, a3 = 0.f;
    if (e == 0) {
        uint su = xw32[(size_t)wid * 32 + d];            // self (prescaled by its dinv)
        gcn2_proc(su, a0, a1, a2, a3);
    }
    int i = RFL(off[wid]), i1 = RFL(off[wid + 1]);
    int nfull = (i1 - i) >> 3;                           // chunks of 8 edges (4 pairs)
    if (nfull > 0) {
        int cA[4], cB[4];
        uint ua[4], ub[4];
        #pragma unroll
        for (int j2 = 0; j2 < 4; ++j2) cA[j2] = col[i + 2 * j2 + e];
        #pragma unroll
        for (int j2 = 0; j2 < 4; ++j2) ua[j2] = xw32[(size_t)cA[j2] * 32 + d];
        if (nfull > 1) {
            #pragma unroll
            for (int j2 = 0; j2 < 4; ++j2) cB[j2] = col[i + 8 + 2 * j2 + e];
        }
        int t = 0;
        while (true) {
            bool hasN = (t + 1 < nfull);
            if (hasN) {
                #pragma unroll
                for (int j2 = 0; j2 < 4; ++j2) ub[j2] = xw32[(size_t)cB[j2] * 32 + d];
            }
            if (t + 2 < nfull) {
                int base = i + 8 * (t + 2);
                #pragma unroll
                for (int j2 = 0; j2 < 4; ++j2) cA[j2] = col[base + 2 * j2 + e];
            }
            #pragma unroll
            for (int j2 = 0; j2 < 4; ++j2) gcn2_proc(ua[j2], a0, a1, a2, a3);
            ++t; if (!hasN) break;
            hasN = (t + 1 < nfull);
            if (hasN) {
                #pragma unroll
                for (int j2 = 0; j2 < 4; ++j2) ua[j2] = xw32[(size_t)cA[j2] * 32 + d];
            }
            if (t + 2 < nfull) {
                int base = i + 8 * (t + 2);
                #pragma unroll
                for (int j2 = 0; j2 < 4; ++j2) cB[j2] = col[base + 2 * j2 + e];
            }
            #pragma unroll
            for (int j2 = 0; j2 < 4; ++j2) gcn2_proc(ub[j2], a0, a1, a2, a3);
            ++t; if (!hasN) break;
        }
        i += nfull * 8;
    }
    for (; i < i1; i += 2) {                             // pair tail, masked
        int idx = i + e;
        uint u = (idx < i1) ? xw32[(size_t)col[idx] * 32 + d] : 0u;   // fp8 0 -> 0.0
        gcn2_proc(u, a0, a1, a2, a3);
    }
    a0 += __shfl_xor(a0, 32);
    a1 += __shfl_xor(a1, 32);
    a2 += __shfl_xor(a2, 32);
    a3 += __shfl_xor(a3, 32);
    if (e == 0) {
        float4 b4 = ((const float4*)bias)[d];
        uint o0 = bf2_pack(fmaxf(di * a0 + b4.x, 0.f), fmaxf(di * a1 + b4.y, 0.f));
        uint o1 = bf2_pack(fmaxf(di * a2 + b4.z, 0.f), fmaxf(di * a3 + b4.w, 0.f));
        y[(size_t)wid * 32 + d] = make_uint2(o0, o1);
    }
}

// ---------------- transformer attention: head-per-lane-group, 3-stage pipeline ----------------
// lane = (h = lane>>3, j = lane&7). Lane holds all 16 q feats of head h, processes edge i+j.
// KV row = 64 dwords; head h occupies dwords [h*8, h*8+8), dword d = [k2d,k2d+1,v2d,v2d+1] fp8.
__device__ __forceinline__ void attn_chunk(uint4 A, uint4 Bv, bool act, const float (&qf)[16],
                                           float& m, float& s, float (&acc)[16]) {
    uint au[8] = {A.x, A.y, A.z, A.w, Bv.x, Bv.y, Bv.z, Bv.w};
    float l = 0.f;
    #pragma unroll
    for (int d = 0; d < 8; ++d) {
        float2 kk = fp8x2_unpack<false>(au[d]);
        l = fmaf(qf[2 * d], kk.x, l);
        l = fmaf(qf[2 * d + 1], kk.y, l);
    }
    if (!act) l = -INFINITY;
    float mx = l;
    mx = fmaxf(mx, __shfl_xor(mx, 1));
    mx = fmaxf(mx, __shfl_xor(mx, 2));
    mx = fmaxf(mx, __shfl_xor(mx, 4));
    if (mx > m) {
        float corr = __expf(m - mx);     // 0 on first real chunk (m=-inf)
        s *= corr;
        #pragma unroll
        for (int f = 0; f < 16; ++f) acc[f] *= corr;
        m = mx;
    }
    float e = act ? __expf(l - m) : 0.f;
    s += e;
    #pragma unroll
    for (int d = 0; d < 8; ++d) {
        float2 vv = fp8x2_unpack<true>(au[d]);
        acc[2 * d] = fmaf(e, vv.x, acc[2 * d]);
        acc[2 * d + 1] = fmaf(e, vv.y, acc[2 * d + 1]);
    }
}

__global__ __launch_bounds__(256) void k_attn(const uint* __restrict__ qb, const uint* __restrict__ kv8,
                                              const int* __restrict__ off, const int* __restrict__ col,
                                              uint* __restrict__ io, int n) {
    int wid = RFL((int)((blockIdx.x * 256 + threadIdx.x) >> 6));
    int lane = threadIdx.x & 63;
    int h = lane >> 3, j = lane & 7;
    if (wid >= n) return;
    float qf[16];
    {
        const uint4* q4 = (const uint4*)(qb + (size_t)wid * 64 + h * 8);
        uint4 qa = q4[0], qc = q4[1];
        uint qu[8] = {qa.x, qa.y, qa.z, qa.w, qc.x, qc.y, qc.z, qc.w};
        #pragma unroll
        for (int d = 0; d < 8; ++d) {
            float2 t = bf2_unpack(qu[d]);
            qf[2 * d] = t.x;
            qf[2 * d + 1] = t.y;
        }
    }
    float acc[16];
    #pragma unroll
    for (int f = 0; f < 16; ++f) acc[f] = 0.f;
    float m = -INFINITY, s = 0.f;
    int i0 = RFL(off[wid]), i1 = RFL(off[wid + 1]);
    int nch = (i1 - i0 + 7) >> 3;   // masked 8-edge chunks
    if (nch > 0) {
        bool actA, actB = false, okA, okB = false;
        int colA, colB = 0;
        uint4 KA0, KA1, KB0, KB1;
        {
            int idx = i0 + j; actA = idx < i1;
            colA = col[actA ? idx : (i1 - 1)];
        }
        {
            const uint4* pb = (const uint4*)(kv8 + ((size_t)(uint)colA << 6) + (h << 3));
            KA0 = pb[0]; KA1 = pb[1]; okA = actA;
        }
        if (nch > 1) {
            int idx = i0 + 8 + j; actB = idx < i1;
            colB = col[actB ? idx : (i1 - 1)];
        }
        int t = 0;
        while (true) {
            bool hasN = (t + 1 < nch);
            if (hasN) {
                const uint4* pb = (const uint4*)(kv8 + ((size_t)(uint)colB << 6) + (h << 3));
                KB0 = pb[0]; KB1 = pb[1]; okB = actB;
            }
            if (t + 2 < nch) {
                int idx = i0 + 8 * (t + 2) + j; actA = idx < i1;
                colA = col[actA ? idx : (i1 - 1)];
            }
            attn_chunk(KA0, KA1, okA, qf, m, s, acc);
            ++t; if (!hasN) break;
            hasN = (t + 1 < nch);
            if (hasN) {
                const uint4* pb = (const uint4*)(kv8 + ((size_t)(uint)colA << 6) + (h << 3));
                KA0 = pb[0]; KA1 = pb[1]; okA = actA;
            }
            if (t + 2 < nch) {
                int idx = i0 + 8 * (t + 2) + j; actB = idx < i1;
                colB = col[actB ? idx : (i1 - 1)];
            }
            attn_chunk(KB0, KB1, okB, qf, m, s, acc);
            ++t; if (!hasN) break;
        }
    }
    // s total over the 8 edge-slot lanes of this head
    s += __shfl_xor(s, 1);
    s += __shfl_xor(s, 2);
    s += __shfl_xor(s, 4);
    // fold acc 16 -> 8 -> 4 -> 2; lane j ends with feats 2j, 2j+1 of head h
    float r8[8];
    #pragma unroll
    for (int f = 0; f < 8; ++f) {
        float send = (j & 4) ? acc[f] : acc[f + 8];
        float recv = __shfl_xor(send, 4);
        r8[f] = ((j & 4) ? acc[f + 8] : acc[f]) + recv;
    }
    float r4[4];
    #pragma unroll
    for (int f = 0; f < 4; ++f) {
        float send = (j & 2) ? r8[f] : r8[f + 4];
        float recv = __shfl_xor(send, 2);
        r4[f] = ((j & 2) ? r8[f + 4] : r8[f]) + recv;
    }
    float r2[2];
    #pragma unroll
    for (int f = 0; f < 2; ++f) {
        float send = (j & 1) ? r4[f] : r4[f + 2];
        float recv = __shfl_xor(send, 1);
        r2[f] = ((j & 1) ? r4[f + 2] : r4[f]) + recv;
    }
    float inv = (1.f / SCL_KV) / fmaxf(s, 1e-16f);
    uint* orow = io + (size_t)wid * 64 + lane;   // uint idx = h*8 + j
    float2 o2 = bf2_unpack(*orow);               // skip connection already there
    o2.x += r2[0] * inv;
    o2.y += r2[1] * inv;
    *orow = bf2_pack(o2.x, o2.y);
}

// ---------------- mean-pool per graph (batch sorted), bf16 in, 64 nodes/block ----------------
__global__ __launch_bounds__(128) void k_pool(const __hip_bfloat16* __restrict__ x, const int* __restrict__ batch,
                                              float* __restrict__ gsum, float* __restrict__ cnt, int n) {
    int t = threadIdx.x;
    int start = blockIdx.x * 64;
    int end = start + 64; if (end > n) end = n;
    if (start >= n) return;
    int cur = batch[start];
    float acc = 0.f;
    int run = 0;
    for (int nn = start; nn < end; ++nn) {
        int g = batch[nn];
        if (g != cur) {
            atomicAdd(&gsum[cur * 128 + t], acc);
            if (t == 0) atomicAdd(&cnt[cur], (float)run);
            acc = 0.f; run = 0; cur = g;
        }
        acc += __bfloat162float(x[(size_t)nn * 128 + t]);
        run++;
    }
    atomicAdd(&gsum[cur * 128 + t], acc);
    if (t == 0) atomicAdd(&cnt[cur], (float)run);
}

// ---------------- FiLM + LSTM + LayerNorm + dueling heads, one block per graph ----------------
__global__ __launch_bounds__(128) void k_final(
    const float* __restrict__ gsum, const float* __restrict__ cnt, const float* __restrict__ w,
    const float* __restrict__ Wgam, const float* __restrict__ bgam,
    const float* __restrict__ Wbet, const float* __restrict__ bbet,
    const float* __restrict__ hprev, const float* __restrict__ cprev,
    const float* __restrict__ Wih, const float* __restrict__ bih,
    const float* __restrict__ Whh, const float* __restrict__ bhh,
    const float* __restrict__ lng, const float* __restrict__ lnb,
    const float* __restrict__ Wa1, const float* __restrict__ ba1,
    const float* __restrict__ Wa2, const float* __restrict__ ba2,
    const float* __restrict__ Wv1, const float* __restrict__ bv1,
    const float* __restrict__ Wv2, const float* __restrict__ bv2,
    float* __restrict__ out_qv, float* __restrict__ out_h, float* __restrict__ out_c) {
    int g = blockIdx.x, t = threadIdx.x;
    __shared__ __align__(16) float ge[128], hp[128], hn[128], r1[128], a1s[128], red[128];
    __shared__ float adv[16], val[2], mu_s, var_s;

    float w0 = w[g * 2 + 0], w1 = w[g * 2 + 1];
    float c = fmaxf(cnt[g], 1.f);
    float mn = gsum[g * 128 + t] / c;
    float gam = w0 * Wgam[2 * t] + w1 * Wgam[2 * t + 1] + bgam[t];
    float bet = w0 * Wbet[2 * t] + w1 * Wbet[2 * t + 1] + bbet[t];
    ge[t] = (1.f + gam) * mn + bet;
    hp[t] = hprev[g * 128 + t];
    __syncthreads();

    float gi = bih[t] + bhh[t];
    float gf = bih[128 + t] + bhh[128 + t];
    float gg = bih[256 + t] + bhh[256 + t];
    float go = bih[384 + t] + bhh[384 + t];
    {
        const float4* ge4 = (const float4*)ge;
        const float4* hp4 = (const float4*)hp;
        const float4* Ai = (const float4*)(Wih + (size_t)t * 128);
        const float4* Af = (const float4*)(Wih + (size_t)(128 + t) * 128);
        const float4* Ag = (const float4*)(Wih + (size_t)(256 + t) * 128);
        const float4* Ao = (const float4*)(Wih + (size_t)(384 + t) * 128);
        const float4* Hi = (const float4*)(Whh + (size_t)t * 128);
        const float4* Hf = (const float4*)(Whh + (size_t)(128 + t) * 128);
        const float4* Hg = (const float4*)(Whh + (size_t)(256 + t) * 128);
        const float4* Ho = (const float4*)(Whh + (size_t)(384 + t) * 128);
        #pragma unroll 4
        for (int k4 = 0; k4 < 32; ++k4) {
            float4 a = ge4[k4], h4 = hp4[k4], u;
            u = Ai[k4]; gi += a.x * u.x + a.y * u.y + a.z * u.z + a.w * u.w;
            u = Hi[k4]; gi += h4.x * u.x + h4.y * u.y + h4.z * u.z + h4.w * u.w;
            u = Af[k4]; gf += a.x * u.x + a.y * u.y + a.z * u.z + a.w * u.w;
            u = Hf[k4]; gf += h4.x * u.x + h4.y * u.y + h4.z * u.z + h4.w * u.w;
            u = Ag[k4]; gg += a.x * u.x + a.y * u.y + a.z * u.z + a.w * u.w;
            u = Hg[k4]; gg += h4.x * u.x + h4.y * u.y + h4.z * u.z + h4.w * u.w;
            u = Ao[k4]; go += a.x * u.x + a.y * u.y + a.z * u.z + a.w * u.w;
            u = Ho[k4]; go += h4.x * u.x + h4.y * u.y + h4.z * u.z + h4.w * u.w;
        }
    }
    float ig = 1.f / (1.f + __expf(-gi));
    float fg = 1.f / (1.f + __expf(-gf));
    float gc = tanhf(gg);
    float og = 1.f / (1.f + __expf(-go));
    float craw = fg * cprev[g * 128 + t] + ig * gc;
    float hraw = og * tanhf(craw);
    out_c[g * 128 + t] = fminf(fmaxf(craw, -1e6f), 1e6f);

    red[t] = hraw;
    __syncthreads();
    for (int s2 = 64; s2 > 0; s2 >>= 1) { if (t < s2) red[t] += red[t + s2]; __syncthreads(); }
    if (t == 0) mu_s = red[0] * (1.f / 128.f);
    __syncthreads();
    float mu = mu_s;
    float d = hraw - mu;
    red[t] = d * d;
    __syncthreads();
    for (int s2 = 64; s2 > 0; s2 >>= 1) { if (t < s2) red[t] += red[t + s2]; __syncthreads(); }
    if (t == 0) var_s = red[0] * (1.f / 128.f);
    __syncthreads();
    float hv = d * rsqrtf(var_s + 1e-5f) * lng[t] + lnb[t];
    hn[t] = hv;
    out_h[g * 128 + t] = hv;
    __syncthreads();

    float accv = bv1[t], acca = ba1[t];
    {
        const float4* hn4 = (const float4*)hn;
        const float4* V1 = (const float4*)(Wv1 + (size_t)t * 128);
        const float4* A1 = (const float4*)(Wa1 + (size_t)t * 128);
        #pragma unroll 4
        for (int k4 = 0; k4 < 32; ++k4) {
            float4 hh = hn4[k4], u;
            u = V1[k4]; accv += hh.x * u.x + hh.y * u.y + hh.z * u.z + hh.w * u.w;
            u = A1[k4]; acca += hh.x * u.x + hh.y * u.y + hh.z * u.z + hh.w * u.w;
        }
    }
    r1[t] = fmaxf(accv, 0.f);
    a1s[t] = fmaxf(acca, 0.f);
    __syncthreads();
    if (t < 2) {
        float s = bv2[t];
        const float4* V2 = (const float4*)(Wv2 + (size_t)t * 128);
        const float4* r4 = (const float4*)r1;
        for (int k4 = 0; k4 < 32; ++k4) { float4 u = V2[k4], rr = r4[k4]; s += rr.x * u.x + rr.y * u.y + rr.z * u.z + rr.w * u.w; }
        val[t] = s;
    }
    if (t < 14) {
        float s = ba2[t];
        const float4* A2 = (const float4*)(Wa2 + (size_t)t * 128);
        const float4* a4 = (const float4*)a1s;
        for (int k4 = 0; k4 < 32; ++k4) { float4 u = A2[k4], aa = a4[k4]; s += aa.x * u.x + aa.y * u.y + aa.z * u.z + aa.w * u.w; }
        adv[t] = s;
    }
    __syncthreads();
    if (t < 14) {
        int o = t & 1;
        float mo = (adv[o] + adv[o + 2] + adv[o + 4] + adv[o + 6] + adv[o + 8] + adv[o + 10] + adv[o + 12]) * (1.f / 7.f);
        float qq = val[o] + adv[t] - mo;
        if (isnan(qq)) qq = 0.f;
        qq = fminf(fmaxf(qq, -100.f), 100.f);
        out_qv[g * 14 + t] = qq;
    }
}

extern "C" void kernel_launch(void* const* d_in, const int* in_sizes, int n_in,
                              void* d_out, int out_size, void* d_ws, size_t ws_size,
                              hipStream_t stream) {
    const float* nf    = (const float*)d_in[0];
    const int*   ei    = (const int*)d_in[1];
    const int*   batch = (const int*)d_in[2];
    const float* w     = (const float*)d_in[3];
    const float* hprev = (const float*)d_in[4];
    const float* cprev = (const float*)d_in[5];
    const float* W_emb = (const float*)d_in[6];  const float* b_emb = (const float*)d_in[7];
    const float* W_g1  = (const float*)d_in[8];  const float* b_g1  = (const float*)d_in[9];
    const float* W_g2  = (const float*)d_in[10]; const float* b_g2  = (const float*)d_in[11];
    const float* Wq    = (const float*)d_in[12]; const float* bq    = (const float*)d_in[13];
    const float* Wk    = (const float*)d_in[14]; const float* bk    = (const float*)d_in[15];
    const float* Wv    = (const float*)d_in[16]; const float* bv    = (const float*)d_in[17];
    const float* Wskip = (const float*)d_in[18]; const float* bskip = (const float*)d_in[19];
    const float* Wgam  = (const float*)d_in[20]; const float* bgam  = (const float*)d_in[21];
    const float* Wbet  = (const float*)d_in[22]; const float* bbet  = (const float*)d_in[23];
    const float* Wih   = (const float*)d_in[24]; const float* bih   = (const float*)d_in[25];
    const float* Whh   = (const float*)d_in[26]; const float* bhh   = (const float*)d_in[27];
    const float* lng   = (const float*)d_in[28]; const float* lnb   = (const float*)d_in[29];
    const float* Wa1   = (const float*)d_in[30]; const float* ba1   = (const float*)d_in[31];
    const float* Wa2   = (const float*)d_in[32]; const float* ba2   = (const float*)d_in[33];
    const float* Wv1   = (const float*)d_in[34]; const float* bv1   = (const float*)d_in[35];
    const float* Wv2   = (const float*)d_in[36]; const float* bv2   = (const float*)d_in[37];

    int N = in_sizes[2];
    int E = in_sizes[1] / 2;
    int B = in_sizes[4] / 128;
    int nbk = (N + 31) >> BK_SH;   // buckets of 32 dst nodes (<= 2048)

    char* p = (char*)d_ws;
    auto alloc = [&](size_t bytes) { char* r = p; p += (bytes + 511) & ~(size_t)511; return r; };
    int*   bcnt   = (int*)alloc((size_t)nbk * 4);
    int*   bcur   = (int*)alloc((size_t)nbk * 4);
    float* gsum   = (float*)alloc((size_t)B * 128 * 4);
    float* cnt    = (float*)alloc((size_t)B * 4);
    size_t zbytes = (size_t)(p - (char*)d_ws);   // region zeroed each call
    int*   boff   = (int*)alloc((size_t)(nbk + 1) * 4);
    uint2* pairs  = (uint2*)alloc((size_t)E * 8);
    int*   off    = (int*)alloc((size_t)(N + 1) * 4);
    int*   col    = (int*)alloc((size_t)E * 4);
    float* dinv   = (float*)alloc((size_t)N * 4);
    __hip_bfloat16* Wc  = (__hip_bfloat16*)alloc((size_t)6 * 16384 * 2);  // bf16 weights: g1,g2,q,k,v,skip
    __hip_bfloat16* X0b = (__hip_bfloat16*)alloc((size_t)N * 128 * 2);    // x0 / x2
    __hip_bfloat16* X1b = (__hip_bfloat16*)alloc((size_t)N * 128 * 2);    // x1
    ushort_t* XW8 = (ushort_t*)alloc((size_t)N * 128);                    // fp8 xw' (prescaled, x32)
    uint*  KV8 = (uint*)alloc((size_t)N * 256);                           // fp8 head-blocked [k,k,v,v] dwords (x16)
    __hip_bfloat16* Cqb = (__hip_bfloat16*)alloc((size_t)N * 128 * 2);    // q bf16 (x 0.25/16)
    __hip_bfloat16* Bb  = (__hip_bfloat16*)alloc((size_t)N * 128 * 2);    // skip + attn out, bf16
    if ((size_t)(p - (char*)d_ws) > ws_size) return;

    (void)hipMemsetAsync(d_ws, 0, zbytes, stream);

    const __hip_bfloat16* Wg1b  = Wc + 0 * 16384;
    const __hip_bfloat16* Wg2b  = Wc + 1 * 16384;
    const __hip_bfloat16* Wqkvs = Wc + 2 * 16384;   // q,k,v,skip contiguous
    k_cvt6<<<384, 256, 0, stream>>>(W_g1, W_g2, Wq, Wk, Wv, Wskip, Wc);

    int gC = (E + CHUNK - 1) / CHUNK;
    k_bcount<<<gC, 1024, 0, stream>>>(ei, bcnt, E, nbk);
    k_bscan<<<1, 1024, 0, stream>>>(bcnt, boff, nbk);
    k_bfill<<<gC, 1024, 0, stream>>>(ei, boff, bcur, pairs, E, nbk);
    k_bucket<<<nbk, 256, 0, stream>>>(pairs, boff, off, dinv, col, N, nbk, E);

    int gN = (N + 3) / 4;       // gather kernels: 4 waves/block, 1 node/wave
    int gM = (N + 63) / 64;     // MFMA kernels: 64 rows/block

    k_linear<32, true, true, __hip_bfloat16><<<2048, 256, 0, stream>>>(nf, W_emb, b_emb, X0b, N);   // x0 bf16
    k_lin_mfma_scale<<<gM, 256, 0, stream>>>(X0b, Wg1b, dinv, XW8, N);                              // xw1' fp8
    k_gcn_agg<<<gN, 256, 0, stream>>>((const uint*)XW8, off, col, dinv, b_g1, (uint2*)X1b, N);      // x1
    k_lin_mfma_scale<<<gM, 256, 0, stream>>>(X1b, Wg2b, dinv, XW8, N);                              // xw2' fp8
    k_gcn_agg<<<gN, 256, 0, stream>>>((const uint*)XW8, off, col, dinv, b_g2, (uint2*)X0b, N);      // x2

    k_qkvs_mfma<<<gM, 256, 0, stream>>>(X0b, Wqkvs, bq, bk, bv, bskip, Cqb, KV8, Bb, N);            // q,KV,skip
    k_attn<<<gN, 256, 0, stream>>>((const uint*)Cqb, KV8, off, col, (uint*)Bb, N);                  // Bb += attn

    k_pool<<<gM, 128, 0, stream>>>(Bb, batch, gsum, cnt, N);

    float* out_qv = (float*)d_out;
    float* out_h  = out_qv + (size_t)B * 14;
    float* out_c  = out_h + (size_t)B * 128;
    k_final<<<B, 128, 0, stream>>>(gsum, cnt, w, Wgam, bgam, Wbet, bbet, hprev, cprev,
                                   Wih, bih, Whh, bhh, lng, lnb,
                                   Wa1, ba1, Wa2, ba2, Wv1, bv1, Wv2, bv2,
                                   out_qv, out_h, out_c);
}